// Round 17
// baseline (380.501 us; speedup 1.0000x reference)
//
#include <hip/hip_runtime.h>
#include <stdint.h>
#include <stdio.h>

#define B_   2
#define T_   1024
#define C_   1024
#define H_   4096
#define ER_  8
#define ES_  2
#define NTOK (B_*T_)   // 2048

typedef __attribute__((ext_vector_type(4))) float  f32x4;
typedef __attribute__((ext_vector_type(8))) __bf16 bf16x8;
typedef __attribute__((ext_vector_type(8))) unsigned short us8;

__device__ __forceinline__ unsigned short f2bf(float f) {
  unsigned u = __builtin_bit_cast(unsigned, f);
  u += 0x7FFFu + ((u >> 16) & 1u);          // RNE
  return (unsigned short)(u >> 16);
}
__device__ __forceinline__ float bf2f(unsigned short s) {
  unsigned u = (unsigned)s << 16;
  return __builtin_bit_cast(float, u);
}

__device__ __forceinline__ void async_ld16(void* lds, const void* g) {
  __builtin_amdgcn_global_load_lds(
      (const __attribute__((address_space(1))) char*)(uintptr_t)g,
      (__attribute__((address_space(3))) char*)(uintptr_t)lds, 16, 0, 0);
}

__device__ __forceinline__ f32x4 mfma16(bf16x8 a, bf16x8 b, f32x4 c) {
  return __builtin_amdgcn_mfma_f32_16x16x32_bf16(a, b, c, 0, 0, 0);
}

// fast exact-enough GELU: tanh form, max |err| vs erf-GELU ~3e-3
__device__ __forceinline__ float gelu_f(float v) {
  float inner = 0.7978845608f * v * (1.0f + 0.044715f * v * v);
  float e = __expf(2.0f * inner);
  return v * (1.0f - __builtin_amdgcn_rcpf(e + 1.0f));
}

// -------------------------------------------- per-token norm scales + routing
__global__ void k_prep(const float* __restrict__ u, const float* __restrict__ gs,
                       const float* __restrict__ gr, const float* __restrict__ cent,
                       __bf16* __restrict__ xns, __bf16* __restrict__ xnr,
                       int* __restrict__ tki, float* __restrict__ tkg)
{
  const int t = blockIdx.x, tid = threadIdx.x;
  float4 v = reinterpret_cast<const float4*>(u + (size_t)t * C_)[tid];
  float ss = v.x*v.x + v.y*v.y + v.z*v.z + v.w*v.w;
  const int c0 = tid * 4;
  float sc[ER_];
  #pragma unroll
  for (int e = 0; e < ER_; ++e) {
    sc[e] = v.x * cent[(c0+0)*ER_ + e] + v.y * cent[(c0+1)*ER_ + e]
          + v.z * cent[(c0+2)*ER_ + e] + v.w * cent[(c0+3)*ER_ + e];
  }
  #pragma unroll
  for (int o = 32; o > 0; o >>= 1) {
    ss += __shfl_down(ss, o);
    #pragma unroll
    for (int e = 0; e < ER_; ++e) sc[e] += __shfl_down(sc[e], o);
  }
  __shared__ float red[4][ER_ + 1];
  __shared__ float sbc;
  const int w = tid >> 6;
  if ((tid & 63) == 0) {
    red[w][0] = ss;
    #pragma unroll
    for (int e = 0; e < ER_; ++e) red[w][1 + e] = sc[e];
  }
  __syncthreads();
  if (tid == 0) {
    float S = red[0][0] + red[1][0] + red[2][0] + red[3][0];
    sbc = rsqrtf(S * (1.0f / C_) + 1.1920929e-07f);
    float p[ER_]; float psum = 0.f;
    #pragma unroll
    for (int e = 0; e < ER_; ++e) {
      float d = red[0][1+e] + red[1][1+e] + red[2][1+e] + red[3][1+e];
      p[e] = 1.f / (1.f + expf(-d));
      psum += p[e];
    }
    int i0 = 0;
    for (int e = 1; e < ER_; ++e) if (p[e] > p[i0]) i0 = e;
    int i1 = -1;
    for (int e = 0; e < ER_; ++e) { if (e == i0) continue; if (i1 < 0 || p[e] > p[i1]) i1 = e; }
    tki[t*2+0] = i0;  tki[t*2+1] = i1;
    tkg[t*2+0] = p[i0] / psum;  tkg[t*2+1] = p[i1] / psum;
  }
  __syncthreads();
  const float s = sbc;
  ushort4 os, orr;
  os.x  = f2bf(v.x * s * gs[c0+0]); os.y  = f2bf(v.y * s * gs[c0+1]);
  os.z  = f2bf(v.z * s * gs[c0+2]); os.w  = f2bf(v.w * s * gs[c0+3]);
  orr.x = f2bf(v.x * s * gr[c0+0]); orr.y = f2bf(v.y * s * gr[c0+1]);
  orr.z = f2bf(v.z * s * gr[c0+2]); orr.w = f2bf(v.w * s * gr[c0+3]);
  reinterpret_cast<ushort4*>(xns)[(size_t)t * (C_/4) + tid] = os;
  reinterpret_cast<ushort4*>(xnr)[(size_t)t * (C_/4) + tid] = orr;
}

// ---------- expert token-list builder + inverse map + PRODUCTIVE WORKLISTS
// GEMM1 geometry: gx1=32 n-blocks, yb = 16 (shared) / ceil(cnt/128) (routed)
// GEMM2 geometry: gx2=8 n-blocks; z<4 shared kc (yb=16), z>=4 routed (e,kc)
__global__ void k_build(const int* __restrict__ tki, const float* __restrict__ tkg,
                        int* __restrict__ listTok, float* __restrict__ listGate,
                        int* __restrict__ offs, int* __restrict__ cnts,
                        int* __restrict__ inv,
                        int* __restrict__ wl1, int* __restrict__ n1,
                        int* __restrict__ wl2, int* __restrict__ n2)
{
  __shared__ int cnt[ER_], cur[ER_], off[ER_];
  __shared__ int zoff1[ES_ + ER_ + 1], zoff2[4 + ER_*2 + 1];
  const int tid = threadIdx.x;
  if (tid < ER_) cnt[tid] = 0;
  __syncthreads();
  for (int i = tid; i < NTOK*2; i += 256) atomicAdd(&cnt[tki[i]], 1);
  __syncthreads();
  if (tid == 0) {
    int a = 0;
    for (int e = 0; e < ER_; ++e) { off[e] = a; cur[e] = a; a += cnt[e]; }
    // GEMM1 worklist offsets
    int s1 = 0;
    for (int z = 0; z < ES_ + ER_; ++z) {
      zoff1[z] = s1;
      int yb = (z < ES_) ? (NTOK / 128) : ((cnt[z - ES_] + 127) >> 7);
      s1 += yb * 32;
    }
    zoff1[ES_ + ER_] = s1;  *n1 = s1;
    // GEMM2 worklist offsets (shared kc=0..3, routed (e,kc) z=4..19)
    int s2 = 0;
    for (int z = 0; z < 4 + ER_*2; ++z) {
      zoff2[z] = s2;
      int yb = (z < 4) ? (NTOK / 128) : ((cnt[(z - 4) >> 1] + 127) >> 7);
      s2 += yb * 8;
    }
    zoff2[4 + ER_*2] = s2;  *n2 = s2;
  }
  __syncthreads();
  for (int i = tid; i < NTOK*2; i += 256) {
    int e = tki[i];
    int p = atomicAdd(&cur[e], 1);
    listTok[p]  = i >> 1;
    listGate[p] = tkg[i];
    inv[i] = p;
  }
  if (tid < ER_) { offs[tid] = off[tid]; cnts[tid] = cnt[tid]; }
  // fill worklists: item = (z<<16) | (yb<<8) | xb
  const int tot1 = zoff1[ES_ + ER_];
  for (int i = tid; i < tot1; i += 256) {
    int z = 0; while (zoff1[z + 1] <= i) ++z;
    int r = i - zoff1[z];
    wl1[i] = (z << 16) | ((r >> 5) << 8) | (r & 31);
  }
  const int tot2 = zoff2[4 + ER_*2];
  for (int i = tid; i < tot2; i += 256) {
    int z = 0; while (zoff2[z + 1] <= i) ++z;
    int r = i - zoff2[z];
    wl2[i] = (z << 16) | ((r >> 3) << 8) | (r & 7);
  }
}

// ---------------- weight transpose + fp32->bf16 ([K][N] -> [N][K]), bf16 LDS
__global__ void k_convT(const float* __restrict__ src, __bf16* __restrict__ dst,
                        int K, int N)
{
  const int e = blockIdx.z;
  src += (size_t)e * K * N;
  unsigned short* d = reinterpret_cast<unsigned short*>(dst) + (size_t)e * K * N;
  const int n0 = blockIdx.x * 64, k0 = blockIdx.y * 64;
  __shared__ unsigned short tb[64][72];
  const int tid = threadIdx.x;
  const int kr = tid >> 4, c4 = (tid & 15) * 4;
  #pragma unroll
  for (int i = 0; i < 4; ++i) {
    const int kk = kr + i * 16;
    float4 v = *reinterpret_cast<const float4*>(&src[(size_t)(k0+kk)*N + n0 + c4]);
    tb[kk][c4+0] = f2bf(v.x); tb[kk][c4+1] = f2bf(v.y);
    tb[kk][c4+2] = f2bf(v.z); tb[kk][c4+3] = f2bf(v.w);
  }
  __syncthreads();
  const int nr = tid >> 2;
  #pragma unroll
  for (int j = 0; j < 2; ++j) {
    const int kc = ((tid & 3) + j * 4) * 8;
    us8 o;
    #pragma unroll
    for (int t2 = 0; t2 < 8; ++t2) o[t2] = tb[kc + t2][nr];
    *reinterpret_cast<us8*>(&d[(size_t)(n0+nr)*K + k0 + kc]) = o;
  }
}

// ------------------------------------------------------------- fused GEMM
// PERSISTENT WORKLIST version of the r12 core (128x128, BK=32, 4 waves,
// 256 thr, dbuf 32KB LDS). Grid = 1024 blocks (4/CU), grid-stride over
// the productive-tile worklist — zero dead blocks, residency pinned.
// [r16 post-mortem: 4-blk grids delivered the same 5.6 TB/s staged rate and
//  occupancy never exceeded 27% — dead-block churn (60-80% of every routed
//  grid) is the remaining suspect for why nominal residency never
//  materializes. fp8 rechecked and rejected: e4m3 mantissa would push
//  absmax ~8-30x past the 0.125 threshold.]
// Item decode: z = code>>16, yb = (code>>8)&255, xb = code&255.
// PHASE 1: z<2  shared expert z (dense)  -> hids cols z*H   (gelu, bf16)
//          z>=2 routed e=z-2 (gathered)  -> hidr slots      (gelu, bf16)
// PHASE 2: z<4  shared kc=z (K-chunk 2048 of 8192): psh[kc] = acc (+b2s @kc0)
//          z>=4 routed (e,kc)=((z-4)>>1,(z-4)&1), K-chunk 2048 of 4096:
//               prt[kc][slot] = acc (+b2r[e] @kc0); bf16 partials, no atomics
struct GP {
  const __bf16 *xns, *xnr, *hids, *hidr, *wts, *wtr;
  const float *b1s, *b1r, *b2s, *b2r;
  __bf16 *hidws, *hidwr;
  unsigned short *psh, *prt;      // bf16 partials
  const int* listTok; const float* listGate; const int* offs; const int* cnts;
  const int *wl1, *n1, *wl2, *n2;
};

template<int PHASE>
__global__ __launch_bounds__(256, 4)
void k_gemm(GP p)
{
  const int* wl  = (PHASE == 1) ? p.wl1 : p.wl2;
  const int  nit = (PHASE == 1) ? *p.n1 : *p.n2;

  __shared__ __align__(16) __bf16 Al[2 * 128 * 32];   // 16 KB
  __shared__ __align__(16) __bf16 Bl[2 * 128 * 32];   // 16 KB

  const int tid = threadIdx.x;
  const int w = tid >> 6, l = tid & 63;
  const int sr = tid >> 2;                                // 0..63
  const int schunk = ((tid & 3) ^ ((sr >> 1) & 3)) * 8;   // swizzled src chunk
  const int wm = (w >> 1) * 64;
  const int wn = (w & 1) * 64;
  const int lr = l & 15, qh = l >> 4;
  const int rchunk = (qh ^ ((lr >> 1) & 3)) * 16;         // swizzled read chunk

  for (int it = blockIdx.x; it < nit; it += gridDim.x) {
    const int code = wl[it];
    const int z  = code >> 16;
    const int yb = (code >> 8) & 255;
    const int xb = code & 255;

    int M, slotbase = 0, kbase = 0, NT, rowmode;   // 0=dense 1=listTok 2=slot
    long KD;
    const __bf16 *Ab, *Wb;
    const float* bias = nullptr;
    __bf16* hb = nullptr; int hstride = 0;
    unsigned short* pout = nullptr;
    int eidx = 0;

    if (PHASE == 1) {
      KD = C_; NT = C_ / 32;
      if (z < ES_) {
        M = NTOK; rowmode = 0; Ab = p.xns;
        Wb = p.wts + (size_t)z * H_ * C_;
        bias = p.b1s + z * H_;
        hb = p.hidws + z * H_; hstride = ES_ * H_;
      } else {
        eidx = z - ES_;
        M = p.cnts[eidx]; slotbase = p.offs[eidx]; rowmode = 1; Ab = p.xnr;
        Wb = p.wtr + (size_t)eidx * H_ * C_;
        bias = p.b1r + eidx * H_;
        hb = p.hidwr + (size_t)slotbase * H_; hstride = H_;
      }
    } else {
      if (z < 4) {
        const int kc = z;
        M = NTOK; rowmode = 0; Ab = p.hids; KD = ES_ * H_;
        kbase = kc * 2048; NT = 2048 / 32;
        Wb = p.wts; bias = (kc == 0) ? p.b2s : nullptr;
        pout = p.psh + (size_t)kc * NTOK * C_;
      } else {
        const int zz = z - 4;
        eidx = zz >> 1; const int kc = zz & 1;
        M = p.cnts[eidx]; slotbase = p.offs[eidx]; rowmode = 2; Ab = p.hidr; KD = H_;
        kbase = kc * 2048; NT = 2048 / 32;
        Wb = p.wtr + (size_t)eidx * C_ * H_;
        bias = (kc == 0) ? (p.b2r + eidx * C_) : nullptr;
        pout = p.prt + (size_t)kc * (NTOK*2) * C_ + (size_t)slotbase * C_;
      }
    }

    const int m0 = yb * 128;
    const int n0 = xb * 128;
    if (m0 >= M) continue;     // defensive; worklist shouldn't contain these

    const __bf16* aptr[2];
    const __bf16* bptr[2];
    #pragma unroll
    for (int i = 0; i < 2; ++i) {
      int rr = i * 64 + sr;
      int ra = m0 + rr; if (ra >= M) ra = M - 1;
      size_t arow;
      if (rowmode == 0)      arow = (size_t)ra;
      else if (rowmode == 1) arow = (size_t)p.listTok[slotbase + ra];
      else                   arow = (size_t)(slotbase + ra);
      aptr[i] = Ab + arow * KD + kbase + schunk;
      bptr[i] = Wb + (size_t)(n0 + rr) * KD + kbase + schunk;
    }

    auto stage = [&](int b, int t) {
      char* ab = (char*)Al + b * 8192 + w * 1024;
      char* bb = (char*)Bl + b * 8192 + w * 1024;
      #pragma unroll
      for (int i = 0; i < 2; ++i) {
        async_ld16(ab + i * 4096, aptr[i] + t * 32);
        async_ld16(bb + i * 4096, bptr[i] + t * 32);
      }
    };

    f32x4 acc[4][4];
    #pragma unroll
    for (int m = 0; m < 4; ++m)
      #pragma unroll
      for (int n = 0; n < 4; ++n) acc[m][n] = (f32x4){0.f, 0.f, 0.f, 0.f};

    auto compute = [&](int b) {
      const char* As = (const char*)Al + b * 8192;
      const char* Bs = (const char*)Bl + b * 8192;
      bf16x8 af[4], bfr[4];
      #pragma unroll
      for (int m = 0; m < 4; ++m)
        af[m] = *reinterpret_cast<const bf16x8*>(As + (wm + m*16 + lr) * 64 + rchunk);
      #pragma unroll
      for (int n = 0; n < 4; ++n)
        bfr[n] = *reinterpret_cast<const bf16x8*>(Bs + (wn + n*16 + lr) * 64 + rchunk);
      #pragma unroll
      for (int m = 0; m < 4; ++m)
        #pragma unroll
        for (int n = 0; n < 4; ++n)
          acc[m][n] = mfma16(af[m], bfr[n], acc[m][n]);
    };

    // clean 2-phase: stage(next) || compute(cur); ONE barrier per tile.
    // (first barrier of this item also fences the previous item's epilogue)
    stage(0, 0);
    __syncthreads();
    int bc = 0;
    for (int t = 0; t < NT; ++t) {
      if (t + 1 < NT) stage(bc ^ 1, t + 1);
      compute(bc);
      __syncthreads();
      bc ^= 1;
    }

    // epilogue — C/D layout: col = lane&15, row = (lane>>4)*4 + reg
    #pragma unroll
    for (int mf = 0; mf < 4; ++mf) {
      const int rbase = m0 + wm + mf*16 + qh * 4;
      #pragma unroll
      for (int rg = 0; rg < 4; ++rg) {
        const int r = rbase + rg;
        if (r >= M) continue;
        if constexpr (PHASE == 1) {
          #pragma unroll
          for (int nf = 0; nf < 4; ++nf) {
            const int col = n0 + wn + nf*16 + lr;
            float v = acc[mf][nf][rg] + bias[col];
            reinterpret_cast<unsigned short*>(hb)[(size_t)r * hstride + col] =
                f2bf(gelu_f(v));
          }
        } else {
          #pragma unroll
          for (int nf = 0; nf < 4; ++nf) {
            const int col = n0 + wn + nf*16 + lr;
            float v = acc[mf][nf][rg];
            if (bias) v += bias[col];
            pout[(size_t)r * C_ + col] = f2bf(v);
          }
        }
      }
    }
  }
}

// ------------------------------------------- final fuse: out = u + sh + routed
__global__ void k_fuse(const float* __restrict__ u,
                       const unsigned short* __restrict__ psh,
                       const unsigned short* __restrict__ prt,
                       const int* __restrict__ inv, const float* __restrict__ tkg,
                       float* __restrict__ out)
{
  const int t = blockIdx.x, tid = threadIdx.x;
  const int c = tid * 4;
  const int s0 = inv[t*2], s1 = inv[t*2+1];
  const float g0 = tkg[t*2], g1 = tkg[t*2+1];
  float4 a = reinterpret_cast<const float4*>(u + (size_t)t * C_)[tid];
  float r[4] = {a.x, a.y, a.z, a.w};
  #pragma unroll
  for (int kc = 0; kc < 4; ++kc) {
    ushort4 q = *reinterpret_cast<const ushort4*>(&psh[((size_t)kc * NTOK + t) * C_ + c]);
    r[0] += bf2f(q.x); r[1] += bf2f(q.y); r[2] += bf2f(q.z); r[3] += bf2f(q.w);
  }
  #pragma unroll
  for (int k = 0; k < 2; ++k) {
    const int s = k ? s1 : s0;
    const float g = k ? g1 : g0;
    ushort4 q0 = *reinterpret_cast<const ushort4*>(&prt[(size_t)s * C_ + c]);
    ushort4 q1 = *reinterpret_cast<const ushort4*>(&prt[((size_t)(NTOK*2) + s) * C_ + c]);
    r[0] += g * (bf2f(q0.x) + bf2f(q1.x));
    r[1] += g * (bf2f(q0.y) + bf2f(q1.y));
    r[2] += g * (bf2f(q0.z) + bf2f(q1.z));
    r[3] += g * (bf2f(q0.w) + bf2f(q1.w));
  }
  float4 o = {r[0], r[1], r[2], r[3]};
  reinterpret_cast<float4*>(out + (size_t)t * C_)[tid] = o;
}

// -----------------------------------------------------------------------------
extern "C" void kernel_launch(void* const* d_in, const int* in_sizes, int n_in,
                              void* d_out, int out_size, void* d_ws, size_t ws_size,
                              hipStream_t stream)
{
  const float* u    = (const float*)d_in[0];
  const float* gs   = (const float*)d_in[1];
  const float* W1s  = (const float*)d_in[2];
  const float* b1s  = (const float*)d_in[3];
  const float* W2s  = (const float*)d_in[4];
  const float* b2s  = (const float*)d_in[5];
  const float* gr   = (const float*)d_in[6];
  const float* W1r  = (const float*)d_in[7];
  const float* b1r  = (const float*)d_in[8];
  const float* W2r  = (const float*)d_in[9];
  const float* b2r  = (const float*)d_in[10];
  const float* cent = (const float*)d_in[11];
  float* out = (float*)d_out;

  char* ws = (char*)d_ws;
  size_t off = 0;
  auto alloc = [&](size_t bytes) -> char* {
    char* p = ws + off;
    off += (bytes + 255) & ~(size_t)255;
    return p;
  };
  __bf16* wbuf = (__bf16*)alloc((size_t)(ES_ + ER_) * H_ * C_ * 2);  // 84 MB
  __bf16* xns  = (__bf16*)alloc((size_t)NTOK * C_ * 2);
  __bf16* xnr  = (__bf16*)alloc((size_t)NTOK * C_ * 2);
  __bf16* hids = (__bf16*)alloc((size_t)NTOK * (ES_*H_) * 2);        // 33.5 MB
  __bf16* hidr = (__bf16*)alloc((size_t)NTOK * 2 * H_ * 2);          // 33.5 MB
  unsigned short* psh = (unsigned short*)alloc((size_t)4 * NTOK * C_ * 2);    // 16.8 MB
  unsigned short* prt = (unsigned short*)alloc((size_t)2 * NTOK*2 * C_ * 2);  // 16.8 MB
  int*    tki      = (int*)  alloc(NTOK * 2 * 4);
  float*  tkg      = (float*)alloc(NTOK * 2 * 4);
  int*    listTok  = (int*)  alloc(NTOK * 2 * 4);
  float*  listGate = (float*)alloc(NTOK * 2 * 4);
  int*    inv      = (int*)  alloc(NTOK * 2 * 4);
  int*    offs     = (int*)  alloc(64);
  int*    cnts     = (int*)  alloc(64);
  int*    wl1      = (int*)  alloc(8192 * 4);
  int*    wl2      = (int*)  alloc(4096 * 4);
  int*    n1       = (int*)  alloc(64);
  int*    n2       = (int*)  alloc(64);
  if (off > ws_size) {
    fprintf(stderr, "ATHENA: WORKSPACE TOO SMALL: need %zu bytes, have %zu\n", off, ws_size);
    return;
  }

  __bf16* wt_s = wbuf;
  __bf16* wt_r = wbuf + (size_t)ES_ * H_ * C_;

  GP p;
  p.xns = xns; p.xnr = xnr; p.hids = hids; p.hidr = hidr;
  p.wts = wt_s; p.wtr = wt_r;
  p.b1s = b1s; p.b1r = b1r; p.b2s = b2s; p.b2r = b2r;
  p.hidws = hids; p.hidwr = hidr;
  p.psh = psh; p.prt = prt;
  p.listTok = listTok; p.listGate = listGate; p.offs = offs; p.cnts = cnts;
  p.wl1 = wl1; p.n1 = n1; p.wl2 = wl2; p.n2 = n2;

  k_prep<<<dim3(NTOK), dim3(256), 0, stream>>>(u, gs, gr, cent, xns, xnr, tki, tkg);
  k_build<<<dim3(1), dim3(256), 0, stream>>>(tki, tkg, listTok, listGate, offs, cnts,
                                             inv, wl1, n1, wl2, n2);

  // W1 [E][C][H] -> bf16 [E*H][C]
  k_convT<<<dim3(H_/64, C_/64, ES_), dim3(256), 0, stream>>>(W1s, wt_s, C_, H_);
  k_convT<<<dim3(H_/64, C_/64, ER_), dim3(256), 0, stream>>>(W1r, wt_r, C_, H_);

  // persistent GEMM1: 1024 blocks (4/CU) grid-stride over ~1536 items
  k_gemm<1><<<dim3(1024), dim3(256), 0, stream>>>(p);

  // W2: shared stacked [2H][C] -> [C][2H]; routed per-expert [H][C] -> [C][H]
  k_convT<<<dim3(C_/64, (ES_*H_)/64, 1), dim3(256), 0, stream>>>(W2s, wt_s, ES_*H_, C_);
  k_convT<<<dim3(C_/64, H_/64, ER_), dim3(256), 0, stream>>>(W2r, wt_r, H_, C_);

  // persistent GEMM2: 1024 blocks grid-stride over ~1024 items
  k_gemm<2><<<dim3(1024), dim3(256), 0, stream>>>(p);

  // fuse: out = u + sum(psh) + g0*(prt0+prt1)[s0] + g1*(prt0+prt1)[s1]
  k_fuse<<<dim3(NTOK), dim3(256), 0, stream>>>(u, psh, prt, inv, tkg, out);
}

// Round 18
// 379.718 us; speedup vs baseline: 1.0021x; 1.0021x over previous
//
#include <hip/hip_runtime.h>
#include <stdint.h>
#include <stdio.h>

#define B_   2
#define T_   1024
#define C_   1024
#define H_   4096
#define ER_  8
#define ES_  2
#define NTOK (B_*T_)   // 2048

typedef __attribute__((ext_vector_type(4))) float  f32x4;
typedef __attribute__((ext_vector_type(8))) __bf16 bf16x8;
typedef __attribute__((ext_vector_type(8))) unsigned short us8;

__device__ __forceinline__ unsigned short f2bf(float f) {
  unsigned u = __builtin_bit_cast(unsigned, f);
  u += 0x7FFFu + ((u >> 16) & 1u);          // RNE
  return (unsigned short)(u >> 16);
}
__device__ __forceinline__ float bf2f(unsigned short s) {
  unsigned u = (unsigned)s << 16;
  return __builtin_bit_cast(float, u);
}

__device__ __forceinline__ void async_ld16(void* lds, const void* g) {
  __builtin_amdgcn_global_load_lds(
      (const __attribute__((address_space(1))) char*)(uintptr_t)g,
      (__attribute__((address_space(3))) char*)(uintptr_t)lds, 16, 0, 0);
}

__device__ __forceinline__ f32x4 mfma16(bf16x8 a, bf16x8 b, f32x4 c) {
  return __builtin_amdgcn_mfma_f32_16x16x32_bf16(a, b, c, 0, 0, 0);
}

// fast exact-enough GELU: tanh form, max |err| vs erf-GELU ~3e-3
__device__ __forceinline__ float gelu_f(float v) {
  float inner = 0.7978845608f * v * (1.0f + 0.044715f * v * v);
  float e = __expf(2.0f * inner);
  return v * (1.0f - __builtin_amdgcn_rcpf(e + 1.0f));
}

// -------------------------------------------- per-token norm scales + routing
__global__ void k_prep(const float* __restrict__ u, const float* __restrict__ gs,
                       const float* __restrict__ gr, const float* __restrict__ cent,
                       __bf16* __restrict__ xns, __bf16* __restrict__ xnr,
                       int* __restrict__ tki, float* __restrict__ tkg)
{
  const int t = blockIdx.x, tid = threadIdx.x;
  float4 v = reinterpret_cast<const float4*>(u + (size_t)t * C_)[tid];
  float ss = v.x*v.x + v.y*v.y + v.z*v.z + v.w*v.w;
  const int c0 = tid * 4;
  float sc[ER_];
  #pragma unroll
  for (int e = 0; e < ER_; ++e) {
    sc[e] = v.x * cent[(c0+0)*ER_ + e] + v.y * cent[(c0+1)*ER_ + e]
          + v.z * cent[(c0+2)*ER_ + e] + v.w * cent[(c0+3)*ER_ + e];
  }
  #pragma unroll
  for (int o = 32; o > 0; o >>= 1) {
    ss += __shfl_down(ss, o);
    #pragma unroll
    for (int e = 0; e < ER_; ++e) sc[e] += __shfl_down(sc[e], o);
  }
  __shared__ float red[4][ER_ + 1];
  __shared__ float sbc;
  const int w = tid >> 6;
  if ((tid & 63) == 0) {
    red[w][0] = ss;
    #pragma unroll
    for (int e = 0; e < ER_; ++e) red[w][1 + e] = sc[e];
  }
  __syncthreads();
  if (tid == 0) {
    float S = red[0][0] + red[1][0] + red[2][0] + red[3][0];
    sbc = rsqrtf(S * (1.0f / C_) + 1.1920929e-07f);
    float p[ER_]; float psum = 0.f;
    #pragma unroll
    for (int e = 0; e < ER_; ++e) {
      float d = red[0][1+e] + red[1][1+e] + red[2][1+e] + red[3][1+e];
      p[e] = 1.f / (1.f + expf(-d));
      psum += p[e];
    }
    int i0 = 0;
    for (int e = 1; e < ER_; ++e) if (p[e] > p[i0]) i0 = e;
    int i1 = -1;
    for (int e = 0; e < ER_; ++e) { if (e == i0) continue; if (i1 < 0 || p[e] > p[i1]) i1 = e; }
    tki[t*2+0] = i0;  tki[t*2+1] = i1;
    tkg[t*2+0] = p[i0] / psum;  tkg[t*2+1] = p[i1] / psum;
  }
  __syncthreads();
  const float s = sbc;
  ushort4 os, orr;
  os.x  = f2bf(v.x * s * gs[c0+0]); os.y  = f2bf(v.y * s * gs[c0+1]);
  os.z  = f2bf(v.z * s * gs[c0+2]); os.w  = f2bf(v.w * s * gs[c0+3]);
  orr.x = f2bf(v.x * s * gr[c0+0]); orr.y = f2bf(v.y * s * gr[c0+1]);
  orr.z = f2bf(v.z * s * gr[c0+2]); orr.w = f2bf(v.w * s * gr[c0+3]);
  reinterpret_cast<ushort4*>(xns)[(size_t)t * (C_/4) + tid] = os;
  reinterpret_cast<ushort4*>(xnr)[(size_t)t * (C_/4) + tid] = orr;
}

// ---------- token-list builder + inverse map + GEMM1 worklist (+conv items)
// GEMM1 items: z<2 shared (yb=16), z>=2 routed (yb=ceil(cnt/128)); xb 0..15.
// Conv items (if fuse): W2 transpose tiles, code bit31 set:
//   0x80000000 | (sel<<20) | (kt<<8) | nt
//   sel=0: W2s stacked [8192][1024]; sel=1..8: W2r expert sel-1 [4096][1024]
__global__ void k_build(const int* __restrict__ tki, const float* __restrict__ tkg,
                        int* __restrict__ listTok, float* __restrict__ listGate,
                        int* __restrict__ offs, int* __restrict__ cnts,
                        int* __restrict__ inv,
                        int* __restrict__ wl1, int* __restrict__ n1, int fuse)
{
  __shared__ int cnt[ER_], cur[ER_], off[ER_];
  __shared__ int zoff1[ES_ + ER_ + 1];
  const int tid = threadIdx.x;
  if (tid < ER_) cnt[tid] = 0;
  __syncthreads();
  for (int i = tid; i < NTOK*2; i += 256) atomicAdd(&cnt[tki[i]], 1);
  __syncthreads();
  if (tid == 0) {
    int a = 0;
    for (int e = 0; e < ER_; ++e) { off[e] = a; cur[e] = a; a += cnt[e]; }
    int s1 = 0;
    for (int z = 0; z < ES_ + ER_; ++z) {
      zoff1[z] = s1;
      int yb = (z < ES_) ? (NTOK / 128) : ((cnt[z - ES_] + 127) >> 7);
      s1 += yb * 16;                      // 16 xb columns (H/256)
    }
    zoff1[ES_ + ER_] = s1;
    *n1 = s1 + (fuse ? 5120 : 0);
  }
  __syncthreads();
  for (int i = tid; i < NTOK*2; i += 256) {
    int e = tki[i];
    int p = atomicAdd(&cur[e], 1);
    listTok[p]  = i >> 1;
    listGate[p] = tkg[i];
    inv[i] = p;
  }
  if (tid < ER_) { offs[tid] = off[tid]; cnts[tid] = cnt[tid]; }
  const int tot1 = zoff1[ES_ + ER_];
  for (int i = tid; i < tot1; i += 256) {
    int z = 0; while (zoff1[z + 1] <= i) ++z;
    int r = i - zoff1[z];
    wl1[i] = (z << 16) | ((r >> 4) << 8) | (r & 15);
  }
  if (fuse) {
    for (int j = tid; j < 5120; j += 256) {
      int code;
      if (j < 1024) code = 0x80000000 | (0 << 20) | ((j >> 3) << 8) | (j & 7);
      else {
        int jj = j - 1024;
        int e = jj >> 9, r = jj & 511;
        code = 0x80000000 | ((e + 1) << 20) | ((r >> 3) << 8) | (r & 7);
      }
      wl1[tot1 + j] = code;
    }
  }
}

// ---------------- weight transpose + fp32->bf16 ([K][N] -> [N][K]), bf16 LDS
__global__ void k_convT(const float* __restrict__ src, __bf16* __restrict__ dst,
                        int K, int N)
{
  const int e = blockIdx.z;
  src += (size_t)e * K * N;
  unsigned short* d = reinterpret_cast<unsigned short*>(dst) + (size_t)e * K * N;
  const int n0 = blockIdx.x * 64, k0 = blockIdx.y * 64;
  __shared__ unsigned short tb[64][72];
  const int tid = threadIdx.x;
  const int kr = tid >> 4, c4 = (tid & 15) * 4;
  #pragma unroll
  for (int i = 0; i < 4; ++i) {
    const int kk = kr + i * 16;
    float4 v = *reinterpret_cast<const float4*>(&src[(size_t)(k0+kk)*N + n0 + c4]);
    tb[kk][c4+0] = f2bf(v.x); tb[kk][c4+1] = f2bf(v.y);
    tb[kk][c4+2] = f2bf(v.z); tb[kk][c4+3] = f2bf(v.w);
  }
  __syncthreads();
  const int nr = tid >> 2;
  #pragma unroll
  for (int j = 0; j < 2; ++j) {
    const int kc = ((tid & 3) + j * 4) * 8;
    us8 o;
    #pragma unroll
    for (int t2 = 0; t2 < 8; ++t2) o[t2] = tb[kc + t2][nr];
    *reinterpret_cast<us8*>(&d[(size_t)(n0+nr)*K + k0 + kc]) = o;
  }
}

struct GP {
  const __bf16 *xns, *xnr, *hids, *hidr, *wts, *wtr;
  const __bf16 *wts2, *wtr2;            // W2t (GEMM2 operands)
  const float *W2s, *W2r;               // raw fp32 W2 (conv source)
  __bf16 *wt2s_w, *wt2r_w;              // conv dest
  const float *b1s, *b1r, *b2s, *b2r;
  __bf16 *hidws, *hidwr;
  unsigned short *psh, *prt;
  const int* listTok; const float* listGate; const int* offs; const int* cnts;
  const int *wl1, *n1;
};

// -------------------- GEMM1 (persistent worklist, 128m x 256n, + conv items)
// r15 core verbatim; conv items backfill idle memory slots with W2 transpose.
__global__ __launch_bounds__(512)
void k_gemm1(GP p)
{
  const int nit = *p.n1;
  __shared__ __align__(16) char smem[49152];
  __bf16* Al = (__bf16*)smem;             // 2*128*32  = 16 KB
  __bf16* Bl = (__bf16*)(smem + 16384);   // 2*256*32  = 32 KB

  const int tid = threadIdx.x;
  const int w = tid >> 6, l = tid & 63;
  const int sr = tid >> 2;                                // 0..127
  const int schunk = ((tid & 3) ^ ((sr >> 1) & 3)) * 8;
  const int wm = (w >> 2) * 64;
  const int wn = (w & 3) * 64;
  const int lr = l & 15, qh = l >> 4;
  const int rchunk = (qh ^ ((lr >> 1) & 3)) * 16;

  for (int it = blockIdx.x; it < nit; it += gridDim.x) {
    const unsigned code = (unsigned)p.wl1[it];

    if (code & 0x80000000u) {
      // ---- conv item: 64k x 128n transpose tile of W2 ----
      const int sel = (code >> 20) & 255;
      const int k0 = ((code >> 8) & 255) * 64;
      const int n0 = (code & 255) * 128;
      const float* src; unsigned short* dst; int K;
      if (sel == 0) { src = p.W2s; dst = (unsigned short*)p.wt2s_w; K = ES_*H_; }
      else {
        int e = sel - 1;
        src = p.W2r + (size_t)e * H_ * C_;
        dst = (unsigned short*)p.wt2r_w + (size_t)e * C_ * H_;
        K = H_;
      }
      unsigned short (*tb)[136] = (unsigned short(*)[136])smem;
      const int kr = tid >> 5, c4 = (tid & 31) * 4;
      #pragma unroll
      for (int i = 0; i < 4; ++i) {
        const int kk = kr + i * 16;
        float4 v = *reinterpret_cast<const float4*>(&src[(size_t)(k0+kk)*C_ + n0 + c4]);
        tb[kk][c4+0] = f2bf(v.x); tb[kk][c4+1] = f2bf(v.y);
        tb[kk][c4+2] = f2bf(v.z); tb[kk][c4+3] = f2bf(v.w);
      }
      __syncthreads();
      const int nr = tid >> 2;                            // 0..127
      #pragma unroll
      for (int j = 0; j < 2; ++j) {
        const int kc = ((tid & 3) + j * 4) * 8;
        us8 o;
        #pragma unroll
        for (int t2 = 0; t2 < 8; ++t2) o[t2] = tb[kc + t2][nr];
        *reinterpret_cast<us8*>(&dst[(size_t)(n0+nr)*K + k0 + kc]) = o;
      }
      __syncthreads();                                    // fence LDS reuse
      continue;
    }

    // ---- GEMM item ----
    const int z  = code >> 16;
    const int yb = (code >> 8) & 255;
    const int xb = code & 255;

    int M, slotbase = 0, rowmode;
    const __bf16 *Ab, *Wb;
    const float* bias;
    __bf16* hb; int hstride;
    if (z < ES_) {
      M = NTOK; rowmode = 0; Ab = p.xns;
      Wb = p.wts + (size_t)z * H_ * C_;
      bias = p.b1s + z * H_;
      hb = p.hidws + z * H_; hstride = ES_ * H_;
    } else {
      int eidx = z - ES_;
      M = p.cnts[eidx]; slotbase = p.offs[eidx]; rowmode = 1; Ab = p.xnr;
      Wb = p.wtr + (size_t)eidx * H_ * C_;
      bias = p.b1r + eidx * H_;
      hb = p.hidwr + (size_t)slotbase * H_; hstride = H_;
    }
    const int m0 = yb * 128;
    const int n0 = xb * 256;
    if (m0 >= M) continue;

    const __bf16* aptr;
    const __bf16* bptr[2];
    {
      int ra = m0 + sr; if (ra >= M) ra = M - 1;
      size_t arow = (rowmode == 0) ? (size_t)ra : (size_t)p.listTok[slotbase + ra];
      aptr = Ab + arow * C_ + schunk;
    }
    #pragma unroll
    for (int i = 0; i < 2; ++i)
      bptr[i] = Wb + (size_t)(n0 + i * 128 + sr) * C_ + schunk;

    auto stage = [&](int b, int t) {
      char* ab = (char*)Al + b * 8192  + w * 1024;
      char* bb = (char*)Bl + b * 16384 + w * 1024;
      async_ld16(ab, aptr + t * 32);
      #pragma unroll
      for (int i = 0; i < 2; ++i)
        async_ld16(bb + i * 8192, bptr[i] + t * 32);
    };

    f32x4 acc[4][4];
    #pragma unroll
    for (int m = 0; m < 4; ++m)
      #pragma unroll
      for (int n = 0; n < 4; ++n) acc[m][n] = (f32x4){0.f, 0.f, 0.f, 0.f};

    auto compute = [&](int b) {
      const char* As = (const char*)Al + b * 8192;
      const char* Bs = (const char*)Bl + b * 16384;
      bf16x8 af[4], bfr[4];
      #pragma unroll
      for (int m = 0; m < 4; ++m)
        af[m] = *reinterpret_cast<const bf16x8*>(As + (wm + m*16 + lr) * 64 + rchunk);
      #pragma unroll
      for (int n = 0; n < 4; ++n)
        bfr[n] = *reinterpret_cast<const bf16x8*>(Bs + (wn + n*16 + lr) * 64 + rchunk);
      #pragma unroll
      for (int m = 0; m < 4; ++m)
        #pragma unroll
        for (int n = 0; n < 4; ++n)
          acc[m][n] = mfma16(af[m], bfr[n], acc[m][n]);
    };

    stage(0, 0);
    __syncthreads();
    int bc = 0;
    const int NT = C_ / 32;
    for (int t = 0; t < NT; ++t) {
      if (t + 1 < NT) stage(bc ^ 1, t + 1);
      compute(bc);
      __syncthreads();
      bc ^= 1;
    }

    #pragma unroll
    for (int mf = 0; mf < 4; ++mf) {
      const int rbase = m0 + wm + mf*16 + qh * 4;
      #pragma unroll
      for (int rg = 0; rg < 4; ++rg) {
        const int r = rbase + rg;
        if (r >= M) continue;
        #pragma unroll
        for (int nf = 0; nf < 4; ++nf) {
          const int col = n0 + wn + nf*16 + lr;
          float v = acc[mf][nf][rg] + bias[col];
          reinterpret_cast<unsigned short*>(hb)[(size_t)r * hstride + col] =
              f2bf(gelu_f(v));
        }
      }
    }
  }
}

// -------------------- GEMM2 (direct, r15 verbatim, reads wt2 buffers)
// z<4 shared kc (K-chunk 2048 of 8192) -> psh[kc]; z>=4 routed (e,kc) -> prt
__global__ __launch_bounds__(512)
void k_gemm2(GP p)
{
  const int z  = blockIdx.z;
  const int xb = blockIdx.x;
  const int yb = blockIdx.y;

  int M, slotbase = 0, kbase, NT, rowmode;
  long KD;
  const __bf16 *Ab, *Wb;
  const float* bias;
  unsigned short* pout;
  if (z < 4) {
    const int kc = z;
    M = NTOK; rowmode = 0; Ab = p.hids; KD = ES_ * H_;
    kbase = kc * 2048; NT = 2048 / 32;
    Wb = p.wts2; bias = (kc == 0) ? p.b2s : nullptr;
    pout = p.psh + (size_t)kc * NTOK * C_;
  } else {
    const int zz = z - 4;
    int eidx = zz >> 1; const int kc = zz & 1;
    M = p.cnts[eidx]; slotbase = p.offs[eidx]; rowmode = 2; Ab = p.hidr; KD = H_;
    kbase = kc * 2048; NT = 2048 / 32;
    Wb = p.wtr2 + (size_t)eidx * C_ * H_;
    bias = (kc == 0) ? (p.b2r + eidx * C_) : nullptr;
    pout = p.prt + (size_t)kc * (NTOK*2) * C_ + (size_t)slotbase * C_;
  }

  const int m0 = yb * 128;
  if (m0 >= M) return;
  const int n0 = xb * 256;

  const int tid = threadIdx.x;
  const int w = tid >> 6, l = tid & 63;

  __shared__ __align__(16) __bf16 Al[2 * 128 * 32];
  __shared__ __align__(16) __bf16 Bl[2 * 256 * 32];

  const int sr = tid >> 2;
  const int schunk = ((tid & 3) ^ ((sr >> 1) & 3)) * 8;
  const __bf16* aptr;
  const __bf16* bptr[2];
  {
    int ra = m0 + sr; if (ra >= M) ra = M - 1;
    size_t arow = (rowmode == 0) ? (size_t)ra : (size_t)(slotbase + ra);
    aptr = Ab + arow * KD + kbase + schunk;
  }
  #pragma unroll
  for (int i = 0; i < 2; ++i)
    bptr[i] = Wb + (size_t)(n0 + i * 128 + sr) * KD + kbase + schunk;

  auto stage = [&](int b, int t) {
    char* ab = (char*)Al + b * 8192  + w * 1024;
    char* bb = (char*)Bl + b * 16384 + w * 1024;
    async_ld16(ab, aptr + t * 32);
    #pragma unroll
    for (int i = 0; i < 2; ++i)
      async_ld16(bb + i * 8192, bptr[i] + t * 32);
  };

  const int wm = (w >> 2) * 64;
  const int wn = (w & 3) * 64;
  const int lr = l & 15, qh = l >> 4;
  const int rchunk = (qh ^ ((lr >> 1) & 3)) * 16;

  f32x4 acc[4][4];
  #pragma unroll
  for (int m = 0; m < 4; ++m)
    #pragma unroll
    for (int n = 0; n < 4; ++n) acc[m][n] = (f32x4){0.f, 0.f, 0.f, 0.f};

  auto compute = [&](int b) {
    const char* As = (const char*)Al + b * 8192;
    const char* Bs = (const char*)Bl + b * 16384;
    bf16x8 af[4], bfr[4];
    #pragma unroll
    for (int m = 0; m < 4; ++m)
      af[m] = *reinterpret_cast<const bf16x8*>(As + (wm + m*16 + lr) * 64 + rchunk);
    #pragma unroll
    for (int n = 0; n < 4; ++n)
      bfr[n] = *reinterpret_cast<const bf16x8*>(Bs + (wn + n*16 + lr) * 64 + rchunk);
    #pragma unroll
    for (int m = 0; m < 4; ++m)
      #pragma unroll
      for (int n = 0; n < 4; ++n)
        acc[m][n] = mfma16(af[m], bfr[n], acc[m][n]);
  };

  stage(0, 0);
  __syncthreads();
  int bc = 0;
  for (int t = 0; t < NT; ++t) {
    if (t + 1 < NT) stage(bc ^ 1, t + 1);
    compute(bc);
    __syncthreads();
    bc ^= 1;
  }

  #pragma unroll
  for (int mf = 0; mf < 4; ++mf) {
    const int rbase = m0 + wm + mf*16 + qh * 4;
    #pragma unroll
    for (int rg = 0; rg < 4; ++rg) {
      const int r = rbase + rg;
      if (r >= M) continue;
      #pragma unroll
      for (int nf = 0; nf < 4; ++nf) {
        const int col = n0 + wn + nf*16 + lr;
        float v = acc[mf][nf][rg];
        if (bias) v += bias[col];
        pout[(size_t)r * C_ + col] = f2bf(v);
      }
    }
  }
}

// ------------------------------------------- final fuse: out = u + sh + routed
__global__ void k_fuse(const float* __restrict__ u,
                       const unsigned short* __restrict__ psh,
                       const unsigned short* __restrict__ prt,
                       const int* __restrict__ inv, const float* __restrict__ tkg,
                       float* __restrict__ out)
{
  const int t = blockIdx.x, tid = threadIdx.x;
  const int c = tid * 4;
  const int s0 = inv[t*2], s1 = inv[t*2+1];
  const float g0 = tkg[t*2], g1 = tkg[t*2+1];
  float4 a = reinterpret_cast<const float4*>(u + (size_t)t * C_)[tid];
  float r[4] = {a.x, a.y, a.z, a.w};
  #pragma unroll
  for (int kc = 0; kc < 4; ++kc) {
    ushort4 q = *reinterpret_cast<const ushort4*>(&psh[((size_t)kc * NTOK + t) * C_ + c]);
    r[0] += bf2f(q.x); r[1] += bf2f(q.y); r[2] += bf2f(q.z); r[3] += bf2f(q.w);
  }
  #pragma unroll
  for (int k = 0; k < 2; ++k) {
    const int s = k ? s1 : s0;
    const float g = k ? g1 : g0;
    ushort4 q0 = *reinterpret_cast<const ushort4*>(&prt[(size_t)s * C_ + c]);
    ushort4 q1 = *reinterpret_cast<const ushort4*>(&prt[((size_t)(NTOK*2) + s) * C_ + c]);
    r[0] += g * (bf2f(q0.x) + bf2f(q1.x));
    r[1] += g * (bf2f(q0.y) + bf2f(q1.y));
    r[2] += g * (bf2f(q0.z) + bf2f(q1.z));
    r[3] += g * (bf2f(q0.w) + bf2f(q1.w));
  }
  float4 o = {r[0], r[1], r[2], r[3]};
  reinterpret_cast<float4*>(out + (size_t)t * C_)[tid] = o;
}

// -----------------------------------------------------------------------------
extern "C" void kernel_launch(void* const* d_in, const int* in_sizes, int n_in,
                              void* d_out, int out_size, void* d_ws, size_t ws_size,
                              hipStream_t stream)
{
  const float* u    = (const float*)d_in[0];
  const float* gs   = (const float*)d_in[1];
  const float* W1s  = (const float*)d_in[2];
  const float* b1s  = (const float*)d_in[3];
  const float* W2s  = (const float*)d_in[4];
  const float* b2s  = (const float*)d_in[5];
  const float* gr   = (const float*)d_in[6];
  const float* W1r  = (const float*)d_in[7];
  const float* b1r  = (const float*)d_in[8];
  const float* W2r  = (const float*)d_in[9];
  const float* b2r  = (const float*)d_in[10];
  const float* cent = (const float*)d_in[11];
  float* out = (float*)d_out;

  char* ws = (char*)d_ws;
  size_t off = 0;
  auto alloc = [&](size_t bytes) -> char* {
    char* p = ws + off;
    off += (bytes + 255) & ~(size_t)255;
    return p;
  };
  __bf16* wbuf = (__bf16*)alloc((size_t)(ES_ + ER_) * H_ * C_ * 2);  // 84 MB (W1t)
  __bf16* xns  = (__bf16*)alloc((size_t)NTOK * C_ * 2);
  __bf16* xnr  = (__bf16*)alloc((size_t)NTOK * C_ * 2);
  __bf16* hids = (__bf16*)alloc((size_t)NTOK * (ES_*H_) * 2);        // 33.5 MB
  __bf16* hidr = (__bf16*)alloc((size_t)NTOK * 2 * H_ * 2);          // 33.5 MB
  unsigned short* psh = (unsigned short*)alloc((size_t)4 * NTOK * C_ * 2);    // 16.8 MB
  unsigned short* prt = (unsigned short*)alloc((size_t)2 * NTOK*2 * C_ * 2);  // 16.8 MB
  int*    tki      = (int*)  alloc(NTOK * 2 * 4);
  float*  tkg      = (float*)alloc(NTOK * 2 * 4);
  int*    listTok  = (int*)  alloc(NTOK * 2 * 4);
  float*  listGate = (float*)alloc(NTOK * 2 * 4);
  int*    inv      = (int*)  alloc(NTOK * 2 * 4);
  int*    offs     = (int*)  alloc(64);
  int*    cnts     = (int*)  alloc(64);
  int*    wl1      = (int*)  alloc(8192 * 4);
  int*    n1       = (int*)  alloc(64);
  const size_t base_need = off;
  if (base_need > ws_size) {
    fprintf(stderr, "ATHENA: WORKSPACE TOO SMALL: need %zu bytes, have %zu\n",
            base_need, ws_size);
    return;
  }
  // second weight buffer for fused W2-conversion (84 MB); fallback = reuse wbuf
  __bf16* wt2 = (__bf16*)alloc((size_t)(ES_ + ER_) * H_ * C_ * 2);
  const int fuse = (off <= ws_size) ? 1 : 0;

  __bf16* wt_s = wbuf;
  __bf16* wt_r = wbuf + (size_t)ES_ * H_ * C_;
  __bf16* wt2_s = fuse ? wt2 : wt_s;
  __bf16* wt2_r = fuse ? (wt2 + (size_t)ES_ * H_ * C_) : wt_r;

  GP p;
  p.xns = xns; p.xnr = xnr; p.hids = hids; p.hidr = hidr;
  p.wts = wt_s; p.wtr = wt_r;
  p.wts2 = wt2_s; p.wtr2 = wt2_r;
  p.W2s = W2s; p.W2r = W2r;
  p.wt2s_w = wt2_s; p.wt2r_w = wt2_r;
  p.b1s = b1s; p.b1r = b1r; p.b2s = b2s; p.b2r = b2r;
  p.hidws = hids; p.hidwr = hidr;
  p.psh = psh; p.prt = prt;
  p.listTok = listTok; p.listGate = listGate; p.offs = offs; p.cnts = cnts;
  p.wl1 = wl1; p.n1 = n1;

  k_prep<<<dim3(NTOK), dim3(256), 0, stream>>>(u, gs, gr, cent, xns, xnr, tki, tkg);
  k_build<<<dim3(1), dim3(256), 0, stream>>>(tki, tkg, listTok, listGate, offs, cnts,
                                             inv, wl1, n1, fuse);

  // W1 [E][C][H] -> bf16 [E*H][C]
  k_convT<<<dim3(H_/64, C_/64, ES_), dim3(256), 0, stream>>>(W1s, wt_s, C_, H_);
  k_convT<<<dim3(H_/64, C_/64, ER_), dim3(256), 0, stream>>>(W1r, wt_r, C_, H_);

  // persistent GEMM1 (+ fused W2 transpose items): 768 blocks (3/CU)
  k_gemm1<<<dim3(768), dim3(512), 0, stream>>>(p);

  if (!fuse) {
    // fallback: sequential W2 conversion into reused wbuf
    k_convT<<<dim3(C_/64, (ES_*H_)/64, 1), dim3(256), 0, stream>>>(W2s, wt2_s, ES_*H_, C_);
    k_convT<<<dim3(C_/64, H_/64, ER_), dim3(256), 0, stream>>>(W2r, wt2_r, H_, C_);
  }

  // GEMM2 (direct, r15 geometry): z = {4 shared kc, 16 routed (e,kc)}
  k_gemm2<<<dim3(4, 16, 4 + ER_*2), dim3(512), 0, stream>>>(p);

  // fuse: out = u + sum(psh) + g0*(prt0+prt1)[s0] + g1*(prt0+prt1)[s1]
  k_fuse<<<dim3(NTOK), dim3(256), 0, stream>>>(u, psh, prt, inv, tkg, out);
}

// Round 19
// 375.663 us; speedup vs baseline: 1.0129x; 1.0108x over previous
//
#include <hip/hip_runtime.h>
#include <stdint.h>
#include <stdio.h>

#define B_   2
#define T_   1024
#define C_   1024
#define H_   4096
#define ER_  8
#define ES_  2
#define NTOK (B_*T_)   // 2048

typedef __attribute__((ext_vector_type(4))) float  f32x4;
typedef __attribute__((ext_vector_type(8))) __bf16 bf16x8;
typedef __attribute__((ext_vector_type(8))) unsigned short us8;

__device__ __forceinline__ unsigned short f2bf(float f) {
  unsigned u = __builtin_bit_cast(unsigned, f);
  u += 0x7FFFu + ((u >> 16) & 1u);          // RNE
  return (unsigned short)(u >> 16);
}
__device__ __forceinline__ float bf2f(unsigned short s) {
  unsigned u = (unsigned)s << 16;
  return __builtin_bit_cast(float, u);
}

__device__ __forceinline__ void async_ld16(void* lds, const void* g) {
  __builtin_amdgcn_global_load_lds(
      (const __attribute__((address_space(1))) char*)(uintptr_t)g,
      (__attribute__((address_space(3))) char*)(uintptr_t)lds, 16, 0, 0);
}

__device__ __forceinline__ f32x4 mfma16(bf16x8 a, bf16x8 b, f32x4 c) {
  return __builtin_amdgcn_mfma_f32_16x16x32_bf16(a, b, c, 0, 0, 0);
}

// fast exact-enough GELU: tanh form, max |err| vs erf-GELU ~3e-3
__device__ __forceinline__ float gelu_f(float v) {
  float inner = 0.7978845608f * v * (1.0f + 0.044715f * v * v);
  float e = __expf(2.0f * inner);
  return v * (1.0f - __builtin_amdgcn_rcpf(e + 1.0f));
}

// -------------------------------------------- per-token norm scales + routing
__global__ void k_prep(const float* __restrict__ u, const float* __restrict__ gs,
                       const float* __restrict__ gr, const float* __restrict__ cent,
                       __bf16* __restrict__ xns, __bf16* __restrict__ xnr,
                       int* __restrict__ tki, float* __restrict__ tkg)
{
  const int t = blockIdx.x, tid = threadIdx.x;
  float4 v = reinterpret_cast<const float4*>(u + (size_t)t * C_)[tid];
  float ss = v.x*v.x + v.y*v.y + v.z*v.z + v.w*v.w;
  const int c0 = tid * 4;
  float sc[ER_];
  #pragma unroll
  for (int e = 0; e < ER_; ++e) {
    sc[e] = v.x * cent[(c0+0)*ER_ + e] + v.y * cent[(c0+1)*ER_ + e]
          + v.z * cent[(c0+2)*ER_ + e] + v.w * cent[(c0+3)*ER_ + e];
  }
  #pragma unroll
  for (int o = 32; o > 0; o >>= 1) {
    ss += __shfl_down(ss, o);
    #pragma unroll
    for (int e = 0; e < ER_; ++e) sc[e] += __shfl_down(sc[e], o);
  }
  __shared__ float red[4][ER_ + 1];
  __shared__ float sbc;
  const int w = tid >> 6;
  if ((tid & 63) == 0) {
    red[w][0] = ss;
    #pragma unroll
    for (int e = 0; e < ER_; ++e) red[w][1 + e] = sc[e];
  }
  __syncthreads();
  if (tid == 0) {
    float S = red[0][0] + red[1][0] + red[2][0] + red[3][0];
    sbc = rsqrtf(S * (1.0f / C_) + 1.1920929e-07f);
    float p[ER_]; float psum = 0.f;
    #pragma unroll
    for (int e = 0; e < ER_; ++e) {
      float d = red[0][1+e] + red[1][1+e] + red[2][1+e] + red[3][1+e];
      p[e] = 1.f / (1.f + expf(-d));
      psum += p[e];
    }
    int i0 = 0;
    for (int e = 1; e < ER_; ++e) if (p[e] > p[i0]) i0 = e;
    int i1 = -1;
    for (int e = 0; e < ER_; ++e) { if (e == i0) continue; if (i1 < 0 || p[e] > p[i1]) i1 = e; }
    tki[t*2+0] = i0;  tki[t*2+1] = i1;
    tkg[t*2+0] = p[i0] / psum;  tkg[t*2+1] = p[i1] / psum;
  }
  __syncthreads();
  const float s = sbc;
  ushort4 os, orr;
  os.x  = f2bf(v.x * s * gs[c0+0]); os.y  = f2bf(v.y * s * gs[c0+1]);
  os.z  = f2bf(v.z * s * gs[c0+2]); os.w  = f2bf(v.w * s * gs[c0+3]);
  orr.x = f2bf(v.x * s * gr[c0+0]); orr.y = f2bf(v.y * s * gr[c0+1]);
  orr.z = f2bf(v.z * s * gr[c0+2]); orr.w = f2bf(v.w * s * gr[c0+3]);
  reinterpret_cast<ushort4*>(xns)[(size_t)t * (C_/4) + tid] = os;
  reinterpret_cast<ushort4*>(xnr)[(size_t)t * (C_/4) + tid] = orr;
}

// ---------- token-list builder + inverse map + GEMM1 worklist (+conv items)
// GEMM1 items: z<2 shared (yb=16), z>=2 routed (yb=ceil(cnt/128)); xb 0..15.
// Conv items (if fuse): W2 transpose tiles, code bit31 set:
//   0x80000000 | (sel<<20) | (kt<<8) | nt
//   sel=0: W2s stacked [8192][1024]; sel=1..8: W2r expert sel-1 [4096][1024]
__global__ void k_build(const int* __restrict__ tki, const float* __restrict__ tkg,
                        int* __restrict__ listTok, float* __restrict__ listGate,
                        int* __restrict__ offs, int* __restrict__ cnts,
                        int* __restrict__ inv,
                        int* __restrict__ wl1, int* __restrict__ n1, int fuse)
{
  __shared__ int cnt[ER_], cur[ER_], off[ER_];
  __shared__ int zoff1[ES_ + ER_ + 1];
  const int tid = threadIdx.x;
  if (tid < ER_) cnt[tid] = 0;
  __syncthreads();
  for (int i = tid; i < NTOK*2; i += 256) atomicAdd(&cnt[tki[i]], 1);
  __syncthreads();
  if (tid == 0) {
    int a = 0;
    for (int e = 0; e < ER_; ++e) { off[e] = a; cur[e] = a; a += cnt[e]; }
    int s1 = 0;
    for (int z = 0; z < ES_ + ER_; ++z) {
      zoff1[z] = s1;
      int yb = (z < ES_) ? (NTOK / 128) : ((cnt[z - ES_] + 127) >> 7);
      s1 += yb * 16;                      // 16 xb columns (H/256)
    }
    zoff1[ES_ + ER_] = s1;
    *n1 = s1 + (fuse ? 5120 : 0);
  }
  __syncthreads();
  for (int i = tid; i < NTOK*2; i += 256) {
    int e = tki[i];
    int p = atomicAdd(&cur[e], 1);
    listTok[p]  = i >> 1;
    listGate[p] = tkg[i];
    inv[i] = p;
  }
  if (tid < ER_) { offs[tid] = off[tid]; cnts[tid] = cnt[tid]; }
  const int tot1 = zoff1[ES_ + ER_];
  for (int i = tid; i < tot1; i += 256) {
    int z = 0; while (zoff1[z + 1] <= i) ++z;
    int r = i - zoff1[z];
    wl1[i] = (z << 16) | ((r >> 4) << 8) | (r & 15);
  }
  if (fuse) {
    for (int j = tid; j < 5120; j += 256) {
      int code;
      if (j < 1024) code = 0x80000000 | (0 << 20) | ((j >> 3) << 8) | (j & 7);
      else {
        int jj = j - 1024;
        int e = jj >> 9, r = jj & 511;
        code = 0x80000000 | ((e + 1) << 20) | ((r >> 3) << 8) | (r & 7);
      }
      wl1[tot1 + j] = code;
    }
  }
}

// ---------------- weight transpose + fp32->bf16 ([K][N] -> [N][K]), bf16 LDS
__global__ void k_convT(const float* __restrict__ src, __bf16* __restrict__ dst,
                        int K, int N)
{
  const int e = blockIdx.z;
  src += (size_t)e * K * N;
  unsigned short* d = reinterpret_cast<unsigned short*>(dst) + (size_t)e * K * N;
  const int n0 = blockIdx.x * 64, k0 = blockIdx.y * 64;
  __shared__ unsigned short tb[64][72];
  const int tid = threadIdx.x;
  const int kr = tid >> 4, c4 = (tid & 15) * 4;
  #pragma unroll
  for (int i = 0; i < 4; ++i) {
    const int kk = kr + i * 16;
    float4 v = *reinterpret_cast<const float4*>(&src[(size_t)(k0+kk)*N + n0 + c4]);
    tb[kk][c4+0] = f2bf(v.x); tb[kk][c4+1] = f2bf(v.y);
    tb[kk][c4+2] = f2bf(v.z); tb[kk][c4+3] = f2bf(v.w);
  }
  __syncthreads();
  const int nr = tid >> 2;
  #pragma unroll
  for (int j = 0; j < 2; ++j) {
    const int kc = ((tid & 3) + j * 4) * 8;
    us8 o;
    #pragma unroll
    for (int t2 = 0; t2 < 8; ++t2) o[t2] = tb[kc + t2][nr];
    *reinterpret_cast<us8*>(&d[(size_t)(n0+nr)*K + k0 + kc]) = o;
  }
}

struct GP {
  const __bf16 *xns, *xnr, *hids, *hidr, *wts, *wtr;
  const __bf16 *wts2, *wtr2;            // W2t (GEMM2 operands)
  const float *W2s, *W2r;               // raw fp32 W2 (conv source)
  __bf16 *wt2s_w, *wt2r_w;              // conv dest
  const float *b1s, *b1r, *b2s, *b2r;
  __bf16 *hidws, *hidwr;
  unsigned short *psh, *prt;
  const int* listTok; const float* listGate; const int* offs; const int* cnts;
  const int *wl1, *n1;
};

// -------------------- GEMM1 (persistent worklist, 128m x 256n, + conv items)
// r15 core; conv items backfill with W2 transpose.  Conv LDS tile stride 130
// u16 (260B = 65 dwords ≡ 1 mod 32): column-read groups (rows {k,k+8,k+16,
// k+24}) hit banks {+0,+8,+16,+24} -> conflict-free; residual nr-pair 2-way
// is free (m136).  [r18 post-mortem: stride 136 ≡ 4 dwords*... gave 8-way
// (3.9M conflicts/dispatch) and cost the fusion's gain.]
__global__ __launch_bounds__(512)
void k_gemm1(GP p)
{
  const int nit = *p.n1;
  __shared__ __align__(16) __bf16 Al[2 * 128 * 32];   // 16 KB
  __shared__ __align__(16) __bf16 Bl[2 * 256 * 32];   // 32 KB (conv tb lives here)

  const int tid = threadIdx.x;
  const int w = tid >> 6, l = tid & 63;
  const int sr = tid >> 2;                                // 0..127
  const int schunk = ((tid & 3) ^ ((sr >> 1) & 3)) * 8;
  const int wm = (w >> 2) * 64;
  const int wn = (w & 3) * 64;
  const int lr = l & 15, qh = l >> 4;
  const int rchunk = (qh ^ ((lr >> 1) & 3)) * 16;

  for (int it = blockIdx.x; it < nit; it += gridDim.x) {
    const unsigned code = (unsigned)p.wl1[it];

    if (code & 0x80000000u) {
      // ---- conv item: 64k x 128n transpose tile of W2 ----
      const int sel = (code >> 20) & 255;
      const int k0 = ((code >> 8) & 255) * 64;
      const int n0 = (code & 255) * 128;
      const float* src; unsigned short* dst; int K;
      if (sel == 0) { src = p.W2s; dst = (unsigned short*)p.wt2s_w; K = ES_*H_; }
      else {
        int e = sel - 1;
        src = p.W2r + (size_t)e * H_ * C_;
        dst = (unsigned short*)p.wt2r_w + (size_t)e * C_ * H_;
        K = H_;
      }
      unsigned short (*tb)[130] = (unsigned short(*)[130])Bl;   // 16.6 KB
      const int kr = tid >> 5, c4 = (tid & 31) * 4;
      #pragma unroll
      for (int i = 0; i < 4; ++i) {
        const int kk = kr + i * 16;
        float4 v = *reinterpret_cast<const float4*>(&src[(size_t)(k0+kk)*C_ + n0 + c4]);
        tb[kk][c4+0] = f2bf(v.x); tb[kk][c4+1] = f2bf(v.y);
        tb[kk][c4+2] = f2bf(v.z); tb[kk][c4+3] = f2bf(v.w);
      }
      __syncthreads();
      const int nr = tid >> 2;                            // 0..127
      #pragma unroll
      for (int j = 0; j < 2; ++j) {
        const int kc = ((tid & 3) + j * 4) * 8;
        us8 o;
        #pragma unroll
        for (int t2 = 0; t2 < 8; ++t2) o[t2] = tb[kc + t2][nr];
        *reinterpret_cast<us8*>(&dst[(size_t)(n0+nr)*K + k0 + kc]) = o;
      }
      __syncthreads();                                    // fence LDS reuse
      continue;
    }

    // ---- GEMM item (r15 core) ----
    const int z  = code >> 16;
    const int yb = (code >> 8) & 255;
    const int xb = code & 255;

    int M, slotbase = 0, rowmode;
    const __bf16 *Ab, *Wb;
    const float* bias;
    __bf16* hb; int hstride;
    if (z < ES_) {
      M = NTOK; rowmode = 0; Ab = p.xns;
      Wb = p.wts + (size_t)z * H_ * C_;
      bias = p.b1s + z * H_;
      hb = p.hidws + z * H_; hstride = ES_ * H_;
    } else {
      int eidx = z - ES_;
      M = p.cnts[eidx]; slotbase = p.offs[eidx]; rowmode = 1; Ab = p.xnr;
      Wb = p.wtr + (size_t)eidx * H_ * C_;
      bias = p.b1r + eidx * H_;
      hb = p.hidwr + (size_t)slotbase * H_; hstride = H_;
    }
    const int m0 = yb * 128;
    const int n0 = xb * 256;
    if (m0 >= M) continue;

    const __bf16* aptr;
    const __bf16* bptr[2];
    {
      int ra = m0 + sr; if (ra >= M) ra = M - 1;
      size_t arow = (rowmode == 0) ? (size_t)ra : (size_t)p.listTok[slotbase + ra];
      aptr = Ab + arow * C_ + schunk;
    }
    #pragma unroll
    for (int i = 0; i < 2; ++i)
      bptr[i] = Wb + (size_t)(n0 + i * 128 + sr) * C_ + schunk;

    auto stage = [&](int b, int t) {
      char* ab = (char*)Al + b * 8192  + w * 1024;
      char* bb = (char*)Bl + b * 16384 + w * 1024;
      async_ld16(ab, aptr + t * 32);
      #pragma unroll
      for (int i = 0; i < 2; ++i)
        async_ld16(bb + i * 8192, bptr[i] + t * 32);
    };

    f32x4 acc[4][4];
    #pragma unroll
    for (int m = 0; m < 4; ++m)
      #pragma unroll
      for (int n = 0; n < 4; ++n) acc[m][n] = (f32x4){0.f, 0.f, 0.f, 0.f};

    auto compute = [&](int b) {
      const char* As = (const char*)Al + b * 8192;
      const char* Bs = (const char*)Bl + b * 16384;
      bf16x8 af[4], bfr[4];
      #pragma unroll
      for (int m = 0; m < 4; ++m)
        af[m] = *reinterpret_cast<const bf16x8*>(As + (wm + m*16 + lr) * 64 + rchunk);
      #pragma unroll
      for (int n = 0; n < 4; ++n)
        bfr[n] = *reinterpret_cast<const bf16x8*>(Bs + (wn + n*16 + lr) * 64 + rchunk);
      #pragma unroll
      for (int m = 0; m < 4; ++m)
        #pragma unroll
        for (int n = 0; n < 4; ++n)
          acc[m][n] = mfma16(af[m], bfr[n], acc[m][n]);
    };

    stage(0, 0);
    __syncthreads();
    int bc = 0;
    const int NT = C_ / 32;
    for (int t = 0; t < NT; ++t) {
      if (t + 1 < NT) stage(bc ^ 1, t + 1);
      compute(bc);
      __syncthreads();
      bc ^= 1;
    }

    #pragma unroll
    for (int mf = 0; mf < 4; ++mf) {
      const int rbase = m0 + wm + mf*16 + qh * 4;
      #pragma unroll
      for (int rg = 0; rg < 4; ++rg) {
        const int r = rbase + rg;
        if (r >= M) continue;
        #pragma unroll
        for (int nf = 0; nf < 4; ++nf) {
          const int col = n0 + wn + nf*16 + lr;
          float v = acc[mf][nf][rg] + bias[col];
          reinterpret_cast<unsigned short*>(hb)[(size_t)r * hstride + col] =
              f2bf(gelu_f(v));
        }
      }
    }
  }
}

// -------------------- GEMM2 (direct, r15 verbatim, reads wt2 buffers)
__global__ __launch_bounds__(512)
void k_gemm2(GP p)
{
  const int z  = blockIdx.z;
  const int xb = blockIdx.x;
  const int yb = blockIdx.y;

  int M, slotbase = 0, kbase, NT, rowmode;
  long KD;
  const __bf16 *Ab, *Wb;
  const float* bias;
  unsigned short* pout;
  if (z < 4) {
    const int kc = z;
    M = NTOK; rowmode = 0; Ab = p.hids; KD = ES_ * H_;
    kbase = kc * 2048; NT = 2048 / 32;
    Wb = p.wts2; bias = (kc == 0) ? p.b2s : nullptr;
    pout = p.psh + (size_t)kc * NTOK * C_;
  } else {
    const int zz = z - 4;
    int eidx = zz >> 1; const int kc = zz & 1;
    M = p.cnts[eidx]; slotbase = p.offs[eidx]; rowmode = 2; Ab = p.hidr; KD = H_;
    kbase = kc * 2048; NT = 2048 / 32;
    Wb = p.wtr2 + (size_t)eidx * C_ * H_;
    bias = (kc == 0) ? (p.b2r + eidx * C_) : nullptr;
    pout = p.prt + (size_t)kc * (NTOK*2) * C_ + (size_t)slotbase * C_;
  }

  const int m0 = yb * 128;
  if (m0 >= M) return;
  const int n0 = xb * 256;

  const int tid = threadIdx.x;
  const int w = tid >> 6, l = tid & 63;

  __shared__ __align__(16) __bf16 Al[2 * 128 * 32];
  __shared__ __align__(16) __bf16 Bl[2 * 256 * 32];

  const int sr = tid >> 2;
  const int schunk = ((tid & 3) ^ ((sr >> 1) & 3)) * 8;
  const __bf16* aptr;
  const __bf16* bptr[2];
  {
    int ra = m0 + sr; if (ra >= M) ra = M - 1;
    size_t arow = (rowmode == 0) ? (size_t)ra : (size_t)(slotbase + ra);
    aptr = Ab + arow * KD + kbase + schunk;
  }
  #pragma unroll
  for (int i = 0; i < 2; ++i)
    bptr[i] = Wb + (size_t)(n0 + i * 128 + sr) * KD + kbase + schunk;

  auto stage = [&](int b, int t) {
    char* ab = (char*)Al + b * 8192  + w * 1024;
    char* bb = (char*)Bl + b * 16384 + w * 1024;
    async_ld16(ab, aptr + t * 32);
    #pragma unroll
    for (int i = 0; i < 2; ++i)
      async_ld16(bb + i * 8192, bptr[i] + t * 32);
  };

  const int wm = (w >> 2) * 64;
  const int wn = (w & 3) * 64;
  const int lr = l & 15, qh = l >> 4;
  const int rchunk = (qh ^ ((lr >> 1) & 3)) * 16;

  f32x4 acc[4][4];
  #pragma unroll
  for (int m = 0; m < 4; ++m)
    #pragma unroll
    for (int n = 0; n < 4; ++n) acc[m][n] = (f32x4){0.f, 0.f, 0.f, 0.f};

  auto compute = [&](int b) {
    const char* As = (const char*)Al + b * 8192;
    const char* Bs = (const char*)Bl + b * 16384;
    bf16x8 af[4], bfr[4];
    #pragma unroll
    for (int m = 0; m < 4; ++m)
      af[m] = *reinterpret_cast<const bf16x8*>(As + (wm + m*16 + lr) * 64 + rchunk);
    #pragma unroll
    for (int n = 0; n < 4; ++n)
      bfr[n] = *reinterpret_cast<const bf16x8*>(Bs + (wn + n*16 + lr) * 64 + rchunk);
    #pragma unroll
    for (int m = 0; m < 4; ++m)
      #pragma unroll
      for (int n = 0; n < 4; ++n)
        acc[m][n] = mfma16(af[m], bfr[n], acc[m][n]);
  };

  stage(0, 0);
  __syncthreads();
  int bc = 0;
  for (int t = 0; t < NT; ++t) {
    if (t + 1 < NT) stage(bc ^ 1, t + 1);
    compute(bc);
    __syncthreads();
    bc ^= 1;
  }

  #pragma unroll
  for (int mf = 0; mf < 4; ++mf) {
    const int rbase = m0 + wm + mf*16 + qh * 4;
    #pragma unroll
    for (int rg = 0; rg < 4; ++rg) {
      const int r = rbase + rg;
      if (r >= M) continue;
      #pragma unroll
      for (int nf = 0; nf < 4; ++nf) {
        const int col = n0 + wn + nf*16 + lr;
        float v = acc[mf][nf][rg];
        if (bias) v += bias[col];
        pout[(size_t)r * C_ + col] = f2bf(v);
      }
    }
  }
}

// ------------------------------------------- final fuse: out = u + sh + routed
__global__ void k_fuse(const float* __restrict__ u,
                       const unsigned short* __restrict__ psh,
                       const unsigned short* __restrict__ prt,
                       const int* __restrict__ inv, const float* __restrict__ tkg,
                       float* __restrict__ out)
{
  const int t = blockIdx.x, tid = threadIdx.x;
  const int c = tid * 4;
  const int s0 = inv[t*2], s1 = inv[t*2+1];
  const float g0 = tkg[t*2], g1 = tkg[t*2+1];
  float4 a = reinterpret_cast<const float4*>(u + (size_t)t * C_)[tid];
  float r[4] = {a.x, a.y, a.z, a.w};
  #pragma unroll
  for (int kc = 0; kc < 4; ++kc) {
    ushort4 q = *reinterpret_cast<const ushort4*>(&psh[((size_t)kc * NTOK + t) * C_ + c]);
    r[0] += bf2f(q.x); r[1] += bf2f(q.y); r[2] += bf2f(q.z); r[3] += bf2f(q.w);
  }
  #pragma unroll
  for (int k = 0; k < 2; ++k) {
    const int s = k ? s1 : s0;
    const float g = k ? g1 : g0;
    ushort4 q0 = *reinterpret_cast<const ushort4*>(&prt[(size_t)s * C_ + c]);
    ushort4 q1 = *reinterpret_cast<const ushort4*>(&prt[((size_t)(NTOK*2) + s) * C_ + c]);
    r[0] += g * (bf2f(q0.x) + bf2f(q1.x));
    r[1] += g * (bf2f(q0.y) + bf2f(q1.y));
    r[2] += g * (bf2f(q0.z) + bf2f(q1.z));
    r[3] += g * (bf2f(q0.w) + bf2f(q1.w));
  }
  float4 o = {r[0], r[1], r[2], r[3]};
  reinterpret_cast<float4*>(out + (size_t)t * C_)[tid] = o;
}

// -----------------------------------------------------------------------------
extern "C" void kernel_launch(void* const* d_in, const int* in_sizes, int n_in,
                              void* d_out, int out_size, void* d_ws, size_t ws_size,
                              hipStream_t stream)
{
  const float* u    = (const float*)d_in[0];
  const float* gs   = (const float*)d_in[1];
  const float* W1s  = (const float*)d_in[2];
  const float* b1s  = (const float*)d_in[3];
  const float* W2s  = (const float*)d_in[4];
  const float* b2s  = (const float*)d_in[5];
  const float* gr   = (const float*)d_in[6];
  const float* W1r  = (const float*)d_in[7];
  const float* b1r  = (const float*)d_in[8];
  const float* W2r  = (const float*)d_in[9];
  const float* b2r  = (const float*)d_in[10];
  const float* cent = (const float*)d_in[11];
  float* out = (float*)d_out;

  char* ws = (char*)d_ws;
  size_t off = 0;
  auto alloc = [&](size_t bytes) -> char* {
    char* p = ws + off;
    off += (bytes + 255) & ~(size_t)255;
    return p;
  };
  __bf16* wbuf = (__bf16*)alloc((size_t)(ES_ + ER_) * H_ * C_ * 2);  // 84 MB (W1t)
  __bf16* xns  = (__bf16*)alloc((size_t)NTOK * C_ * 2);
  __bf16* xnr  = (__bf16*)alloc((size_t)NTOK * C_ * 2);
  __bf16* hids = (__bf16*)alloc((size_t)NTOK * (ES_*H_) * 2);        // 33.5 MB
  __bf16* hidr = (__bf16*)alloc((size_t)NTOK * 2 * H_ * 2);          // 33.5 MB
  unsigned short* psh = (unsigned short*)alloc((size_t)4 * NTOK * C_ * 2);    // 16.8 MB
  unsigned short* prt = (unsigned short*)alloc((size_t)2 * NTOK*2 * C_ * 2);  // 16.8 MB
  int*    tki      = (int*)  alloc(NTOK * 2 * 4);
  float*  tkg      = (float*)alloc(NTOK * 2 * 4);
  int*    listTok  = (int*)  alloc(NTOK * 2 * 4);
  float*  listGate = (float*)alloc(NTOK * 2 * 4);
  int*    inv      = (int*)  alloc(NTOK * 2 * 4);
  int*    offs     = (int*)  alloc(64);
  int*    cnts     = (int*)  alloc(64);
  int*    wl1      = (int*)  alloc(8192 * 4);
  int*    n1       = (int*)  alloc(64);
  const size_t base_need = off;
  if (base_need > ws_size) {
    fprintf(stderr, "ATHENA: WORKSPACE TOO SMALL: need %zu bytes, have %zu\n",
            base_need, ws_size);
    return;
  }
  // second weight buffer for fused W2-conversion (84 MB); fallback = reuse wbuf
  __bf16* wt2 = (__bf16*)alloc((size_t)(ES_ + ER_) * H_ * C_ * 2);
  const int fuse = (off <= ws_size) ? 1 : 0;

  __bf16* wt_s = wbuf;
  __bf16* wt_r = wbuf + (size_t)ES_ * H_ * C_;
  __bf16* wt2_s = fuse ? wt2 : wt_s;
  __bf16* wt2_r = fuse ? (wt2 + (size_t)ES_ * H_ * C_) : wt_r;

  GP p;
  p.xns = xns; p.xnr = xnr; p.hids = hids; p.hidr = hidr;
  p.wts = wt_s; p.wtr = wt_r;
  p.wts2 = wt2_s; p.wtr2 = wt2_r;
  p.W2s = W2s; p.W2r = W2r;
  p.wt2s_w = wt2_s; p.wt2r_w = wt2_r;
  p.b1s = b1s; p.b1r = b1r; p.b2s = b2s; p.b2r = b2r;
  p.hidws = hids; p.hidwr = hidr;
  p.psh = psh; p.prt = prt;
  p.listTok = listTok; p.listGate = listGate; p.offs = offs; p.cnts = cnts;
  p.wl1 = wl1; p.n1 = n1;

  k_prep<<<dim3(NTOK), dim3(256), 0, stream>>>(u, gs, gr, cent, xns, xnr, tki, tkg);
  k_build<<<dim3(1), dim3(256), 0, stream>>>(tki, tkg, listTok, listGate, offs, cnts,
                                             inv, wl1, n1, fuse);

  // W1 [E][C][H] -> bf16 [E*H][C]
  k_convT<<<dim3(H_/64, C_/64, ES_), dim3(256), 0, stream>>>(W1s, wt_s, C_, H_);
  k_convT<<<dim3(H_/64, C_/64, ER_), dim3(256), 0, stream>>>(W1r, wt_r, C_, H_);

  // persistent GEMM1 (+ fused W2 transpose items): 768 blocks (3/CU)
  k_gemm1<<<dim3(768), dim3(512), 0, stream>>>(p);

  if (!fuse) {
    // fallback: sequential W2 conversion into reused wbuf
    k_convT<<<dim3(C_/64, (ES_*H_)/64, 1), dim3(256), 0, stream>>>(W2s, wt2_s, ES_*H_, C_);
    k_convT<<<dim3(C_/64, H_/64, ER_), dim3(256), 0, stream>>>(W2r, wt2_r, H_, C_);
  }

  // GEMM2 (direct, r15 geometry): z = {4 shared kc, 16 routed (e,kc)}
  k_gemm2<<<dim3(4, 16, 4 + ER_*2), dim3(512), 0, stream>>>(p);

  // fuse: out = u + sum(psh) + g0*(prt0+prt1)[s0] + g1*(prt0+prt1)[s1]
  k_fuse<<<dim3(NTOK), dim3(256), 0, stream>>>(u, psh, prt, inv, tkg, out);
}

// Round 20
// 365.167 us; speedup vs baseline: 1.0420x; 1.0287x over previous
//
#include <hip/hip_runtime.h>
#include <stdint.h>
#include <stdio.h>

#define B_   2
#define T_   1024
#define C_   1024
#define H_   4096
#define ER_  8
#define ES_  2
#define NTOK (B_*T_)   // 2048

typedef __attribute__((ext_vector_type(4))) float  f32x4;
typedef __attribute__((ext_vector_type(8))) __bf16 bf16x8;
typedef __attribute__((ext_vector_type(8))) unsigned short us8;

__device__ __forceinline__ unsigned short f2bf(float f) {
  unsigned u = __builtin_bit_cast(unsigned, f);
  u += 0x7FFFu + ((u >> 16) & 1u);          // RNE
  return (unsigned short)(u >> 16);
}
__device__ __forceinline__ float bf2f(unsigned short s) {
  unsigned u = (unsigned)s << 16;
  return __builtin_bit_cast(float, u);
}

__device__ __forceinline__ void async_ld16(void* lds, const void* g) {
  __builtin_amdgcn_global_load_lds(
      (const __attribute__((address_space(1))) char*)(uintptr_t)g,
      (__attribute__((address_space(3))) char*)(uintptr_t)lds, 16, 0, 0);
}

__device__ __forceinline__ f32x4 mfma16(bf16x8 a, bf16x8 b, f32x4 c) {
  return __builtin_amdgcn_mfma_f32_16x16x32_bf16(a, b, c, 0, 0, 0);
}

// fast exact-enough GELU: tanh form, max |err| vs erf-GELU ~3e-3
__device__ __forceinline__ float gelu_f(float v) {
  float inner = 0.7978845608f * v * (1.0f + 0.044715f * v * v);
  float e = __expf(2.0f * inner);
  return v * (1.0f - __builtin_amdgcn_rcpf(e + 1.0f));
}

// -------------------------------------------- per-token norm scales + routing
__global__ void k_prep(const float* __restrict__ u, const float* __restrict__ gs,
                       const float* __restrict__ gr, const float* __restrict__ cent,
                       __bf16* __restrict__ xns, __bf16* __restrict__ xnr,
                       int* __restrict__ tki, float* __restrict__ tkg)
{
  const int t = blockIdx.x, tid = threadIdx.x;
  float4 v = reinterpret_cast<const float4*>(u + (size_t)t * C_)[tid];
  float ss = v.x*v.x + v.y*v.y + v.z*v.z + v.w*v.w;
  const int c0 = tid * 4;
  float sc[ER_];
  #pragma unroll
  for (int e = 0; e < ER_; ++e) {
    sc[e] = v.x * cent[(c0+0)*ER_ + e] + v.y * cent[(c0+1)*ER_ + e]
          + v.z * cent[(c0+2)*ER_ + e] + v.w * cent[(c0+3)*ER_ + e];
  }
  #pragma unroll
  for (int o = 32; o > 0; o >>= 1) {
    ss += __shfl_down(ss, o);
    #pragma unroll
    for (int e = 0; e < ER_; ++e) sc[e] += __shfl_down(sc[e], o);
  }
  __shared__ float red[4][ER_ + 1];
  __shared__ float sbc;
  const int w = tid >> 6;
  if ((tid & 63) == 0) {
    red[w][0] = ss;
    #pragma unroll
    for (int e = 0; e < ER_; ++e) red[w][1 + e] = sc[e];
  }
  __syncthreads();
  if (tid == 0) {
    float S = red[0][0] + red[1][0] + red[2][0] + red[3][0];
    sbc = rsqrtf(S * (1.0f / C_) + 1.1920929e-07f);
    float p[ER_]; float psum = 0.f;
    #pragma unroll
    for (int e = 0; e < ER_; ++e) {
      float d = red[0][1+e] + red[1][1+e] + red[2][1+e] + red[3][1+e];
      p[e] = 1.f / (1.f + expf(-d));
      psum += p[e];
    }
    int i0 = 0;
    for (int e = 1; e < ER_; ++e) if (p[e] > p[i0]) i0 = e;
    int i1 = -1;
    for (int e = 0; e < ER_; ++e) { if (e == i0) continue; if (i1 < 0 || p[e] > p[i1]) i1 = e; }
    tki[t*2+0] = i0;  tki[t*2+1] = i1;
    tkg[t*2+0] = p[i0] / psum;  tkg[t*2+1] = p[i1] / psum;
  }
  __syncthreads();
  const float s = sbc;
  ushort4 os, orr;
  os.x  = f2bf(v.x * s * gs[c0+0]); os.y  = f2bf(v.y * s * gs[c0+1]);
  os.z  = f2bf(v.z * s * gs[c0+2]); os.w  = f2bf(v.w * s * gs[c0+3]);
  orr.x = f2bf(v.x * s * gr[c0+0]); orr.y = f2bf(v.y * s * gr[c0+1]);
  orr.z = f2bf(v.z * s * gr[c0+2]); orr.w = f2bf(v.w * s * gr[c0+3]);
  reinterpret_cast<ushort4*>(xns)[(size_t)t * (C_/4) + tid] = os;
  reinterpret_cast<ushort4*>(xnr)[(size_t)t * (C_/4) + tid] = orr;
}

// ------------------------------ expert token-list builder (+ inverse mapping)
__global__ void k_build(const int* __restrict__ tki, const float* __restrict__ tkg,
                        int* __restrict__ listTok, float* __restrict__ listGate,
                        int* __restrict__ offs, int* __restrict__ cnts,
                        int* __restrict__ inv)
{
  __shared__ int cnt[ER_], cur[ER_], off[ER_];
  const int tid = threadIdx.x;
  if (tid < ER_) cnt[tid] = 0;
  __syncthreads();
  for (int i = tid; i < NTOK*2; i += 256) atomicAdd(&cnt[tki[i]], 1);
  __syncthreads();
  if (tid == 0) {
    int a = 0;
    for (int e = 0; e < ER_; ++e) { off[e] = a; cur[e] = a; a += cnt[e]; }
  }
  __syncthreads();
  for (int i = tid; i < NTOK*2; i += 256) {
    int e = tki[i];
    int p = atomicAdd(&cur[e], 1);
    listTok[p]  = i >> 1;
    listGate[p] = tkg[i];
    inv[i] = p;
  }
  if (tid < ER_) { offs[tid] = off[tid]; cnts[tid] = cnt[tid]; }
}

// ---------------- weight transpose + fp32->bf16 ([K][N] -> [N][K]), bf16 LDS
__global__ void k_convT(const float* __restrict__ src, __bf16* __restrict__ dst,
                        int K, int N)
{
  const int e = blockIdx.z;
  src += (size_t)e * K * N;
  unsigned short* d = reinterpret_cast<unsigned short*>(dst) + (size_t)e * K * N;
  const int n0 = blockIdx.x * 64, k0 = blockIdx.y * 64;
  __shared__ unsigned short tb[64][72];
  const int tid = threadIdx.x;
  const int kr = tid >> 4, c4 = (tid & 15) * 4;
  #pragma unroll
  for (int i = 0; i < 4; ++i) {
    const int kk = kr + i * 16;
    float4 v = *reinterpret_cast<const float4*>(&src[(size_t)(k0+kk)*N + n0 + c4]);
    tb[kk][c4+0] = f2bf(v.x); tb[kk][c4+1] = f2bf(v.y);
    tb[kk][c4+2] = f2bf(v.z); tb[kk][c4+3] = f2bf(v.w);
  }
  __syncthreads();
  const int nr = tid >> 2;
  #pragma unroll
  for (int j = 0; j < 2; ++j) {
    const int kc = ((tid & 3) + j * 4) * 8;
    us8 o;
    #pragma unroll
    for (int t2 = 0; t2 < 8; ++t2) o[t2] = tb[kc + t2][nr];
    *reinterpret_cast<us8*>(&d[(size_t)(n0+nr)*K + k0 + kc]) = o;
  }
}

// ------------------------------------------------------------- fused GEMM
// r12 configuration verbatim — best measured (365.3 us total).
// 128x128 tile, BK=32, 4 waves, 256 threads, dbuf 32KB LDS, 4 blocks/CU.
// Clean 2-phase: stage(next) -> compute(cur) -> ONE __syncthreads per tile.
// Session conclusion: binding constraint is per-CU global_load_lds service
// (~45 B/cyc/CU -> ~6.8 TB/s chip-wide staged ceiling, measured plateau
// 5.5-7 TB/s across 7 loop-structure variants), with tile intensity capped
// at 64-87 fl/B by the VGPR/co-residency tradeoff (256^2 tiles -> 1 blk/CU
// -> rate halves). Floor: 137 GFLOP/87 fl/B/6 TB/s + conv 503MB@HBM ~= 360us.
// PHASE 1: z<2  shared expert z (dense)  -> hids cols z*H   (gelu, bf16)
//          z>=2 routed e=z-2 (gathered)  -> hidr slots      (gelu, bf16)
// PHASE 2: z<4  shared kc=z (K-chunk 2048 of 8192): psh[kc] = acc (+b2s @kc0)
//          z>=4 routed (e,kc)=((z-4)>>1,(z-4)&1), K-chunk 2048 of 4096:
//               prt[kc][slot] = acc (+b2r[e] @kc0); bf16 partials, no atomics
struct GP {
  const __bf16 *xns, *xnr, *hids, *hidr, *wts, *wtr;
  const float *b1s, *b1r, *b2s, *b2r;
  __bf16 *hidws, *hidwr;
  unsigned short *psh, *prt;      // bf16 partials
  const int* listTok; const float* listGate; const int* offs; const int* cnts;
};

template<int PHASE>
__global__ __launch_bounds__(256, 4)
void k_gemm(GP p)
{
  const int z  = blockIdx.z;
  const int xb = blockIdx.x;    // n-block
  const int yb = blockIdx.y;    // m-block

  int M, slotbase = 0, kbase = 0, NT, rowmode;   // 0=dense 1=listTok 2=slot
  long KD;
  const __bf16 *Ab, *Wb;
  const float* bias = nullptr;
  __bf16* hb = nullptr; int hstride = 0;
  unsigned short* pout = nullptr;
  int eidx = 0;

  if (PHASE == 1) {
    KD = C_; NT = C_ / 32;
    if (z < ES_) {
      M = NTOK; rowmode = 0; Ab = p.xns;
      Wb = p.wts + (size_t)z * H_ * C_;
      bias = p.b1s + z * H_;
      hb = p.hidws + z * H_; hstride = ES_ * H_;
    } else {
      eidx = z - ES_;
      M = p.cnts[eidx]; slotbase = p.offs[eidx]; rowmode = 1; Ab = p.xnr;
      Wb = p.wtr + (size_t)eidx * H_ * C_;
      bias = p.b1r + eidx * H_;
      hb = p.hidwr + (size_t)slotbase * H_; hstride = H_;
    }
  } else {
    if (z < 4) {
      const int kc = z;
      M = NTOK; rowmode = 0; Ab = p.hids; KD = ES_ * H_;
      kbase = kc * 2048; NT = 2048 / 32;
      Wb = p.wts; bias = (kc == 0) ? p.b2s : nullptr;
      pout = p.psh + (size_t)kc * NTOK * C_;
    } else {
      const int zz = z - 4;
      eidx = zz >> 1; const int kc = zz & 1;
      M = p.cnts[eidx]; slotbase = p.offs[eidx]; rowmode = 2; Ab = p.hidr; KD = H_;
      kbase = kc * 2048; NT = 2048 / 32;
      Wb = p.wtr + (size_t)eidx * C_ * H_;
      bias = (kc == 0) ? (p.b2r + eidx * C_) : nullptr;
      pout = p.prt + (size_t)kc * (NTOK*2) * C_ + (size_t)slotbase * C_;
    }
  }

  const int m0 = yb * 128;
  if (m0 >= M) return;
  const int n0 = xb * 128;

  const int tid = threadIdx.x;
  const int w = tid >> 6, l = tid & 63;

  __shared__ __align__(16) __bf16 Al[2 * 128 * 32];   // 16 KB
  __shared__ __align__(16) __bf16 Bl[2 * 128 * 32];   // 16 KB

  // staging: instr i covers rows i*64 + (tid>>2); 4 threads x 16B per 64B row.
  // Source k-chunk XOR-swizzled by (row>>1)&3; LDS dest linear (rule 21).
  const int sr = tid >> 2;                                // 0..63
  const int schunk = ((tid & 3) ^ ((sr >> 1) & 3)) * 8;   // elems
  const __bf16* aptr[2];
  const __bf16* bptr[2];
  #pragma unroll
  for (int i = 0; i < 2; ++i) {
    int rr = i * 64 + sr;
    int ra = m0 + rr; if (ra >= M) ra = M - 1;
    size_t arow;
    if (rowmode == 0)      arow = (size_t)ra;
    else if (rowmode == 1) arow = (size_t)p.listTok[slotbase + ra];
    else                   arow = (size_t)(slotbase + ra);
    aptr[i] = Ab + arow * KD + kbase + schunk;
    bptr[i] = Wb + (size_t)(n0 + rr) * KD + kbase + schunk;
  }

  auto stage = [&](int b, int t) {
    char* ab = (char*)Al + b * 8192 + w * 1024;
    char* bb = (char*)Bl + b * 8192 + w * 1024;
    #pragma unroll
    for (int i = 0; i < 2; ++i) {
      async_ld16(ab + i * 4096, aptr[i] + t * 32);
      async_ld16(bb + i * 4096, bptr[i] + t * 32);
    }
  };

  // fragment geometry: wave (w>>1) m-half, (w&1) n-half
  const int wm = (w >> 1) * 64;
  const int wn = (w & 1) * 64;
  const int lr = l & 15, qh = l >> 4;
  const int rchunk = (qh ^ ((lr >> 1) & 3)) * 16;   // swizzled 16B read chunk

  f32x4 acc[4][4];
  #pragma unroll
  for (int m = 0; m < 4; ++m)
    #pragma unroll
    for (int n = 0; n < 4; ++n) acc[m][n] = (f32x4){0.f, 0.f, 0.f, 0.f};

  auto compute = [&](int b) {
    const char* As = (const char*)Al + b * 8192;
    const char* Bs = (const char*)Bl + b * 8192;
    bf16x8 af[4], bfr[4];
    #pragma unroll
    for (int m = 0; m < 4; ++m)
      af[m] = *reinterpret_cast<const bf16x8*>(As + (wm + m*16 + lr) * 64 + rchunk);
    #pragma unroll
    for (int n = 0; n < 4; ++n)
      bfr[n] = *reinterpret_cast<const bf16x8*>(Bs + (wn + n*16 + lr) * 64 + rchunk);
    #pragma unroll
    for (int m = 0; m < 4; ++m)
      #pragma unroll
      for (int n = 0; n < 4; ++n)
        acc[m][n] = mfma16(af[m], bfr[n], acc[m][n]);
  };

  // ---- clean 2-phase: stage(next) || compute(cur); ONE barrier per tile ----
  stage(0, 0);
  __syncthreads();
  int bc = 0;
  for (int t = 0; t < NT; ++t) {
    if (t + 1 < NT) stage(bc ^ 1, t + 1);
    compute(bc);
    __syncthreads();
    bc ^= 1;
  }

  // ---- epilogue — C/D layout: col = lane&15, row = (lane>>4)*4 + reg ----
  #pragma unroll
  for (int mf = 0; mf < 4; ++mf) {
    const int rbase = m0 + wm + mf*16 + qh * 4;
    #pragma unroll
    for (int rg = 0; rg < 4; ++rg) {
      const int r = rbase + rg;
      if (r >= M) continue;
      if constexpr (PHASE == 1) {
        #pragma unroll
        for (int nf = 0; nf < 4; ++nf) {
          const int col = n0 + wn + nf*16 + lr;
          float v = acc[mf][nf][rg] + bias[col];
          reinterpret_cast<unsigned short*>(hb)[(size_t)r * hstride + col] =
              f2bf(gelu_f(v));
        }
      } else {
        #pragma unroll
        for (int nf = 0; nf < 4; ++nf) {
          const int col = n0 + wn + nf*16 + lr;
          float v = acc[mf][nf][rg];
          if (bias) v += bias[col];
          pout[(size_t)r * C_ + col] = f2bf(v);
        }
      }
    }
  }
}

// ------------------------------------------- final fuse: out = u + sh + routed
__global__ void k_fuse(const float* __restrict__ u,
                       const unsigned short* __restrict__ psh,
                       const unsigned short* __restrict__ prt,
                       const int* __restrict__ inv, const float* __restrict__ tkg,
                       float* __restrict__ out)
{
  const int t = blockIdx.x, tid = threadIdx.x;
  const int c = tid * 4;
  const int s0 = inv[t*2], s1 = inv[t*2+1];
  const float g0 = tkg[t*2], g1 = tkg[t*2+1];
  float4 a = reinterpret_cast<const float4*>(u + (size_t)t * C_)[tid];
  float r[4] = {a.x, a.y, a.z, a.w};
  #pragma unroll
  for (int kc = 0; kc < 4; ++kc) {
    ushort4 q = *reinterpret_cast<const ushort4*>(&psh[((size_t)kc * NTOK + t) * C_ + c]);
    r[0] += bf2f(q.x); r[1] += bf2f(q.y); r[2] += bf2f(q.z); r[3] += bf2f(q.w);
  }
  #pragma unroll
  for (int k = 0; k < 2; ++k) {
    const int s = k ? s1 : s0;
    const float g = k ? g1 : g0;
    ushort4 q0 = *reinterpret_cast<const ushort4*>(&prt[(size_t)s * C_ + c]);
    ushort4 q1 = *reinterpret_cast<const ushort4*>(&prt[((size_t)(NTOK*2) + s) * C_ + c]);
    r[0] += g * (bf2f(q0.x) + bf2f(q1.x));
    r[1] += g * (bf2f(q0.y) + bf2f(q1.y));
    r[2] += g * (bf2f(q0.z) + bf2f(q1.z));
    r[3] += g * (bf2f(q0.w) + bf2f(q1.w));
  }
  float4 o = {r[0], r[1], r[2], r[3]};
  reinterpret_cast<float4*>(out + (size_t)t * C_)[tid] = o;
}

// -----------------------------------------------------------------------------
extern "C" void kernel_launch(void* const* d_in, const int* in_sizes, int n_in,
                              void* d_out, int out_size, void* d_ws, size_t ws_size,
                              hipStream_t stream)
{
  const float* u    = (const float*)d_in[0];
  const float* gs   = (const float*)d_in[1];
  const float* W1s  = (const float*)d_in[2];
  const float* b1s  = (const float*)d_in[3];
  const float* W2s  = (const float*)d_in[4];
  const float* b2s  = (const float*)d_in[5];
  const float* gr   = (const float*)d_in[6];
  const float* W1r  = (const float*)d_in[7];
  const float* b1r  = (const float*)d_in[8];
  const float* W2r  = (const float*)d_in[9];
  const float* b2r  = (const float*)d_in[10];
  const float* cent = (const float*)d_in[11];
  float* out = (float*)d_out;

  char* ws = (char*)d_ws;
  size_t off = 0;
  auto alloc = [&](size_t bytes) -> char* {
    char* p = ws + off;
    off += (bytes + 255) & ~(size_t)255;
    return p;
  };
  __bf16* wbuf = (__bf16*)alloc((size_t)(ES_ + ER_) * H_ * C_ * 2);  // 84 MB
  __bf16* xns  = (__bf16*)alloc((size_t)NTOK * C_ * 2);
  __bf16* xnr  = (__bf16*)alloc((size_t)NTOK * C_ * 2);
  __bf16* hids = (__bf16*)alloc((size_t)NTOK * (ES_*H_) * 2);        // 33.5 MB
  __bf16* hidr = (__bf16*)alloc((size_t)NTOK * 2 * H_ * 2);          // 33.5 MB
  unsigned short* psh = (unsigned short*)alloc((size_t)4 * NTOK * C_ * 2);    // 16.8 MB
  unsigned short* prt = (unsigned short*)alloc((size_t)2 * NTOK*2 * C_ * 2);  // 16.8 MB
  int*    tki      = (int*)  alloc(NTOK * 2 * 4);
  float*  tkg      = (float*)alloc(NTOK * 2 * 4);
  int*    listTok  = (int*)  alloc(NTOK * 2 * 4);
  float*  listGate = (float*)alloc(NTOK * 2 * 4);
  int*    inv      = (int*)  alloc(NTOK * 2 * 4);
  int*    offs     = (int*)  alloc(64);
  int*    cnts     = (int*)  alloc(64);
  if (off > ws_size) {
    fprintf(stderr, "ATHENA: WORKSPACE TOO SMALL: need %zu bytes, have %zu\n", off, ws_size);
    return;
  }

  __bf16* wt_s = wbuf;
  __bf16* wt_r = wbuf + (size_t)ES_ * H_ * C_;

  GP p;
  p.xns = xns; p.xnr = xnr; p.hids = hids; p.hidr = hidr;
  p.wts = wt_s; p.wtr = wt_r;
  p.b1s = b1s; p.b1r = b1r; p.b2s = b2s; p.b2r = b2r;
  p.hidws = hids; p.hidwr = hidr;
  p.psh = psh; p.prt = prt;
  p.listTok = listTok; p.listGate = listGate; p.offs = offs; p.cnts = cnts;

  k_prep<<<dim3(NTOK), dim3(256), 0, stream>>>(u, gs, gr, cent, xns, xnr, tki, tkg);
  k_build<<<dim3(1), dim3(256), 0, stream>>>(tki, tkg, listTok, listGate, offs, cnts, inv);

  // W1 [E][C][H] -> bf16 [E*H][C]
  k_convT<<<dim3(H_/64, C_/64, ES_), dim3(256), 0, stream>>>(W1s, wt_s, C_, H_);
  k_convT<<<dim3(H_/64, C_/64, ER_), dim3(256), 0, stream>>>(W1r, wt_r, C_, H_);

  // fused GEMM1: z = {2 shared, 8 routed}; x = 32 n-blocks (H/128), y = 16 m
  k_gemm<1><<<dim3(32, 16, ES_ + ER_), dim3(256), 0, stream>>>(p);

  // W2: shared stacked [2H][C] -> [C][2H]; routed per-expert [H][C] -> [C][H]
  k_convT<<<dim3(C_/64, (ES_*H_)/64, 1), dim3(256), 0, stream>>>(W2s, wt_s, ES_*H_, C_);
  k_convT<<<dim3(C_/64, H_/64, ER_), dim3(256), 0, stream>>>(W2r, wt_r, H_, C_);

  // fused GEMM2 -> bf16 partials: z = {4 shared kc, 16 routed (e,kc)};
  // x = 8 n-blocks (C/128), y = 16 m-blocks
  k_gemm<2><<<dim3(8, 16, 4 + ER_*2), dim3(256), 0, stream>>>(p);

  // fuse: out = u + sum(psh) + g0*(prt0+prt1)[s0] + g1*(prt0+prt1)[s1]
  k_fuse<<<dim3(NTOK), dim3(256), 0, stream>>>(u, psh, prt, inv, tkg, out);
}